// Round 4
// baseline (31893.555 us; speedup 1.0000x reference)
//
#include <hip/hip_runtime.h>
#include <hip/hip_bf16.h>

// VRAE forward on gfx950. R4: inputs/outputs are FP32 (per reference dtypes) —
// R1-R3 failed because fp32 buffers were misread as bf16 (odd 16-bit halves are
// mantissa bits -> random 1e38/NaN "weights"; R3's finite 3.3e38 absmax is the
// smoking gun). MFMA path uses bf16 hi/lo weight planes (prep kernel, ws) and
// 3-term products for ~fp32 accuracy through the 512-step recurrences.

typedef __bf16 bf16;
typedef __bf16 bf16x8 __attribute__((ext_vector_type(8)));
typedef float f32x4 __attribute__((ext_vector_type(4)));

#define MFMA(a,b,c) __builtin_amdgcn_mfma_f32_16x16x32_bf16((a),(b),(c),0,0,0)

__device__ __forceinline__ float sigm_(float x){ return 1.f/(1.f+__expf(-x)); }
__device__ __forceinline__ float tanh_(float x){
  x = fminf(15.f, fmaxf(-15.f, x));
  float e = __expf(2.f*x);
  return (e-1.f)/(e+1.f);
}
// scrub NaN/Inf -> 0 (diagnostic belt-and-suspenders; not fast-math so no fold)
__device__ __forceinline__ float fin_(float v){ return (v - v == 0.0f) ? v : 0.0f; }

// ---------------------------------------------------------------------------
// Weight prep: fp32 -> bf16 hi/lo planes in ws.
// ---------------------------------------------------------------------------
struct PrepJobs {
  const float* src[9];
  bf16* hi[9];
  bf16* lo[9];
  int n[9];
};

__global__ void prep_w(PrepJobs J){
  const int stride = gridDim.x*blockDim.x;
  const int t0 = blockIdx.x*blockDim.x + threadIdx.x;
  for (int j=0;j<9;++j){
    const float* __restrict__ s = J.src[j];
    bf16* __restrict__ h = J.hi[j];
    bf16* __restrict__ l = J.lo[j];
    const int n = J.n[j];
    for (int i=t0;i<n;i+=stride){
      float v = fin_(s[i]);
      bf16 hh = (bf16)v;
      h[i] = hh;
      l[i] = (bf16)(v - (float)hh);
    }
  }
}

// ---------------------------------------------------------------------------
// Encoder recurrent kernel. grid=32: blockIdx>>4 = dir, blockIdx&15 = batch
// slice of 16. block=256 (4 waves); wave w owns gate cols g0 = w*96+i*16, i<6.
// F32IN: seqIn is fp32 (layer 0, x); else bf16 (inter-layer seq).
// ---------------------------------------------------------------------------
template<int KIN, bool F32IN>
__global__ __launch_bounds__(256,1)
void enc_rec(const void* __restrict__ seqIn_,  // [256,512,KIN] fp32|bf16
             bf16* __restrict__ seqOut,        // [256,512,256] or null
             const bf16* __restrict__ WihHi_, const bf16* __restrict__ WihLo_, // [2,384,KIN]
             const bf16* __restrict__ WhhHi_, const bf16* __restrict__ WhhLo_, // [2,384,128]
             const float* __restrict__ bih_, const float* __restrict__ bhh_,   // [2,384]
             const int* __restrict__ lengths,
             float* __restrict__ hFo, float* __restrict__ hBo)                 // [256,128] or null
{
  constexpr int NKS = KIN/32;
  const int tid = threadIdx.x;
  const int wave = tid>>6;
  const int lane = tid&63;
  const int lh = lane&15;
  const int quad = lane>>4;
  const int dir = blockIdx.x>>4;
  const int b0 = (blockIdx.x&15)*16;

  const bf16* __restrict__ WihHi = WihHi_ + (size_t)dir*384*KIN;
  const bf16* __restrict__ WihLo = WihLo_ + (size_t)dir*384*KIN;
  const bf16* __restrict__ WhhHi = WhhHi_ + (size_t)dir*384*128;
  const bf16* __restrict__ WhhLo = WhhLo_ + (size_t)dir*384*128;
  const float* __restrict__ bih = bih_ + dir*384;
  const float* __restrict__ bhh = bhh_ + dir*384;

  __shared__ float comb[16*388];   // fused r,z preacts (cols 0..255) + gi_n (256..383)
  __shared__ float nbuf[16*132];   // gh_n
  __shared__ bf16 hHi[16*136];
  __shared__ bf16 hLo[16*136];

  for (int i=tid;i<16*136;i+=256){ hHi[i]=(bf16)0.f; hLo[i]=(bf16)0.f; }

  const int lenA = lengths[b0+lh];
  const int gm = tid&15;
  const int gj0 = (tid>>4)*8;
  const int lenG = lengths[b0+gm];
  const int Tmax = lengths[b0];    // sorted desc -> slice max

  float biasF[6], biasN[6];
#pragma unroll
  for (int i=0;i<6;++i){
    int g0 = wave*96+i*16, gcol = g0+lh;
    float bi = bih[gcol], bh = bhh[gcol];
    biasF[i] = (g0<256)? bi+bh : bi;
    biasN[i] = bh;
  }
  __syncthreads();

  for (int t=0;t<Tmax;++t){
    int tbA = dir ? (lenA-1-t) : t;
    tbA = tbA < 0 ? 0 : tbA;

    // ---- input A-fragments ----
    bf16x8 aInHi[NKS], aInLo[F32IN? NKS : 1];
    if constexpr (F32IN){
      const float* arow = (const float*)seqIn_ + ((size_t)(b0+lh)*512 + tbA)*KIN + quad*8;
#pragma unroll
      for (int ks=0;ks<NKS;++ks){
#pragma unroll
        for (int e=0;e<8;++e){
          float v = arow[ks*32 + e];
          bf16 hh = (bf16)v;
          aInHi[ks][e] = hh;
          aInLo[ks][e] = (bf16)(v - (float)hh);
        }
      }
    } else {
      const bf16* arow = (const bf16*)seqIn_ + ((size_t)(b0+lh)*512 + tbA)*KIN + quad*8;
#pragma unroll
      for (int ks=0;ks<NKS;++ks) aInHi[ks] = *(const bf16x8*)(arow + ks*32);
    }
    // ---- hidden A-fragments ----
    bf16x8 aHi[4], aLo[4];
#pragma unroll
    for (int ks=0;ks<4;++ks){
      aHi[ks] = *(const bf16x8*)&hHi[lh*136 + ks*32 + quad*8];
      aLo[ks] = *(const bf16x8*)&hLo[lh*136 + ks*32 + quad*8];
    }

    // ---- MFMA phase ----
#pragma unroll
    for (int i=0;i<6;++i){
      const int g0 = wave*96+i*16;
      const int gcol = g0+lh;
      const bf16* bgiH = WihHi + (size_t)gcol*KIN + quad*8;
      const bf16* bgiL = WihLo + (size_t)gcol*KIN + quad*8;
      const bf16* bghH = WhhHi + (size_t)gcol*128 + quad*8;
      const bf16* bghL = WhhLo + (size_t)gcol*128 + quad*8;
      if (g0 < 256){   // r,z: gi+gh fused in one accumulator
        f32x4 acc = {0.f,0.f,0.f,0.f};
#pragma unroll
        for (int ks=0;ks<NKS;++ks){
          bf16x8 bh = *(const bf16x8*)(bgiH + ks*32);
          bf16x8 bl = *(const bf16x8*)(bgiL + ks*32);
          acc = MFMA(aInHi[ks], bh, acc);
          if constexpr (F32IN) acc = MFMA(aInLo[ks], bh, acc);
          acc = MFMA(aInHi[ks], bl, acc);
        }
#pragma unroll
        for (int ks=0;ks<4;++ks){
          bf16x8 bh = *(const bf16x8*)(bghH + ks*32);
          bf16x8 bl = *(const bf16x8*)(bghL + ks*32);
          acc = MFMA(aHi[ks], bh, acc);
          acc = MFMA(aLo[ks], bh, acc);
          acc = MFMA(aHi[ks], bl, acc);
        }
#pragma unroll
        for (int r=0;r<4;++r) comb[(quad*4+r)*388 + gcol] = acc[r] + biasF[i];
      } else {         // n: keep gi and gh separate (r scales gh_n only)
        f32x4 ai = {0.f,0.f,0.f,0.f}, ah = {0.f,0.f,0.f,0.f};
#pragma unroll
        for (int ks=0;ks<NKS;++ks){
          bf16x8 bh = *(const bf16x8*)(bgiH + ks*32);
          bf16x8 bl = *(const bf16x8*)(bgiL + ks*32);
          ai = MFMA(aInHi[ks], bh, ai);
          if constexpr (F32IN) ai = MFMA(aInLo[ks], bh, ai);
          ai = MFMA(aInHi[ks], bl, ai);
        }
#pragma unroll
        for (int ks=0;ks<4;++ks){
          bf16x8 bh = *(const bf16x8*)(bghH + ks*32);
          bf16x8 bl = *(const bf16x8*)(bghL + ks*32);
          ah = MFMA(aHi[ks], bh, ah);
          ah = MFMA(aLo[ks], bh, ah);
          ah = MFMA(aHi[ks], bl, ah);
        }
#pragma unroll
        for (int r=0;r<4;++r){
          int m = quad*4+r;
          comb[m*388 + gcol] = ai[r] + biasF[i];
          nbuf[m*132 + (gcol-256)] = ah[r] + biasN[i];
        }
      }
    }
    __syncthreads();

    // ---- gate phase: thread owns (row gm, units gj0..gj0+7) ----
    const bool valid = (t < lenG);
    bf16x8 ov;
#pragma unroll
    for (int e=0;e<8;++e){
      const int j = gj0+e;
      float r = sigm_(comb[gm*388 + j]);
      float z = sigm_(comb[gm*388 + 128 + j]);
      float n = tanh_(comb[gm*388 + 256 + j] + r*nbuf[gm*132 + j]);
      float hold = (float)hHi[gm*136+j] + (float)hLo[gm*136+j];
      float hnew = fin_((1.f-z)*n + z*hold);
      float hsel = valid? hnew : hold;
      bf16 hi = (bf16)hsel;
      hHi[gm*136+j] = hi;
      hLo[gm*136+j] = (bf16)(hsel - (float)hi);
      ov[e] = (bf16)hnew;
    }
    if (valid && seqOut){
      int tb = dir? (lenG-1-t) : t;
      *(bf16x8*)(seqOut + ((size_t)(b0+gm)*512 + tb)*256 + dir*128 + gj0) = ov;
    }
    __syncthreads();
  }

  float* hout = dir? hBo : hFo;
  if (hout){
#pragma unroll
    for (int e=0;e<8;++e){
      int j = gj0+e;
      hout[(size_t)(b0+gm)*128 + j] = fin_((float)hHi[gm*136+j] + (float)hLo[gm*136+j]);
    }
  }
}

// ---------------------------------------------------------------------------
// Latent: mean/logvar/z/h_init. grid=256 (block per batch row), block=64. fp32.
// ---------------------------------------------------------------------------
__global__ void latent_k(const float* __restrict__ hF, const float* __restrict__ hB,
                         const float* __restrict__ eps,
                         const float* __restrict__ Wm, const float* __restrict__ bm,
                         const float* __restrict__ Wl, const float* __restrict__ bl,
                         const float* __restrict__ Wz, const float* __restrict__ bz,
                         float* __restrict__ out_mean, float* __restrict__ out_logvar,
                         float* __restrict__ hInit)
{
  const int b = blockIdx.x, tid = threadIdx.x;
  __shared__ float hc[256];
  __shared__ float mv[64];
  __shared__ float zz[32];
  for (int k=tid;k<256;k+=64) hc[k] = fin_((k<128)? hF[(size_t)b*128+k] : hB[(size_t)b*128+k-128]);
  __syncthreads();
  {
    const int i = tid & 31;
    const float* W = (tid<32)? Wm : Wl;
    float acc = (tid<32)? bm[i] : bl[i];
    for (int k=0;k<256;++k) acc += hc[k]*W[i*256+k];
    acc = fin_(acc);
    mv[tid] = acc;
    if (tid<32) out_mean[b*32+i] = acc;
    else        out_logvar[b*32+(tid-32)] = acc;
  }
  __syncthreads();
  if (tid<32) zz[tid] = fin_(mv[tid] + __expf(0.5f*mv[32+tid]) * eps[b*32+tid]);
  __syncthreads();
  for (int j=tid;j<128;j+=64){
    float a = bz[j];
    for (int k=0;k<32;++k) a += zz[k]*Wz[j*32+k];
    hInit[(size_t)b*128 + j] = tanh_(fin_(a));
  }
}

// ---------------------------------------------------------------------------
// Decoder: 2-layer GRU + output projection, autoregressive T=512.
// grid=16 (batch slices of 16), block=256. 5 phases per step.
// ---------------------------------------------------------------------------
__global__ __launch_bounds__(256,1)
void dec_rec(const float* __restrict__ hInit,
             const bf16* __restrict__ W0iH, const bf16* __restrict__ W0iL,  // [384,32]
             const bf16* __restrict__ W0hH, const bf16* __restrict__ W0hL,  // [384,128]
             const bf16* __restrict__ W1iH, const bf16* __restrict__ W1iL,  // [384,128]
             const bf16* __restrict__ W1hH, const bf16* __restrict__ W1hL,  // [384,128]
             const bf16* __restrict__ WoH,  const bf16* __restrict__ WoL,   // [32,128]
             const float* __restrict__ bih0, const float* __restrict__ bhh0,
             const float* __restrict__ bih1, const float* __restrict__ bhh1,
             const float* __restrict__ bout,
             float* __restrict__ rec)        // [256,512,32] (d_out)
{
  const int tid=threadIdx.x, wave=tid>>6, lane=tid&63, lh=lane&15, quad=lane>>4;
  const int b0 = blockIdx.x*16;
  const int gm = tid&15, gj0=(tid>>4)*8;

  __shared__ float comb[16*388];
  __shared__ float nbuf[16*132];
  __shared__ bf16 h1Hi[16*136], h1Lo[16*136], h2Hi[16*136], h2Lo[16*136];
  __shared__ bf16 pHi[16*40], pLo[16*40];

#pragma unroll
  for (int e=0;e<8;++e){
    int j=gj0+e;
    float v = fin_(hInit[(size_t)(b0+gm)*128 + j]);
    bf16 hi=(bf16)v, lo=(bf16)(v-(float)hi);
    h1Hi[gm*136+j]=hi; h1Lo[gm*136+j]=lo;
    h2Hi[gm*136+j]=hi; h2Lo[gm*136+j]=lo;
  }
  for (int i=tid;i<16*40;i+=256){ pHi[i]=(bf16)0.f; pLo[i]=(bf16)0.f; }

  float c1F[6], c1N[6], c2F[6], c2N[6];
#pragma unroll
  for (int i=0;i<6;++i){
    int g0=wave*96+i*16, gcol=g0+lh;
    c1F[i] = (g0<256)? bih0[gcol]+bhh0[gcol] : bih0[gcol];  c1N[i]=bhh0[gcol];
    c2F[i] = (g0<256)? bih1[gcol]+bhh1[gcol] : bih1[gcol];  c2N[i]=bhh1[gcol];
  }
  const float bo = (wave<2)? bout[wave*16+lh] : 0.f;
  __syncthreads();

  for (int t=0;t<512;++t){
    // ---- cell1 preacts: gi = pred@W0i^T (K=32), gh = h1@W0h^T (K=128) ----
    bf16x8 aP0 = *(const bf16x8*)&pHi[lh*40 + quad*8];
    bf16x8 aP1 = *(const bf16x8*)&pLo[lh*40 + quad*8];
    bf16x8 aHi[4], aLo[4];
#pragma unroll
    for (int ks=0;ks<4;++ks){
      aHi[ks] = *(const bf16x8*)&h1Hi[lh*136+ks*32+quad*8];
      aLo[ks] = *(const bf16x8*)&h1Lo[lh*136+ks*32+quad*8];
    }
#pragma unroll
    for (int i=0;i<6;++i){
      int g0=wave*96+i*16, gcol=g0+lh;
      bf16x8 giH = *(const bf16x8*)(W0iH + (size_t)gcol*32 + quad*8);
      bf16x8 giL = *(const bf16x8*)(W0iL + (size_t)gcol*32 + quad*8);
      const bf16* ghH = W0hH + (size_t)gcol*128 + quad*8;
      const bf16* ghL = W0hL + (size_t)gcol*128 + quad*8;
      if (g0<256){
        f32x4 acc={0.f,0.f,0.f,0.f};
        acc=MFMA(aP0,giH,acc); acc=MFMA(aP1,giH,acc); acc=MFMA(aP0,giL,acc);
#pragma unroll
        for (int ks=0;ks<4;++ks){
          bf16x8 bh=*(const bf16x8*)(ghH+ks*32);
          bf16x8 bl=*(const bf16x8*)(ghL+ks*32);
          acc=MFMA(aHi[ks],bh,acc); acc=MFMA(aLo[ks],bh,acc); acc=MFMA(aHi[ks],bl,acc);
        }
#pragma unroll
        for (int r=0;r<4;++r) comb[(quad*4+r)*388+gcol]=acc[r]+c1F[i];
      } else {
        f32x4 ai={0.f,0.f,0.f,0.f}, ah={0.f,0.f,0.f,0.f};
        ai=MFMA(aP0,giH,ai); ai=MFMA(aP1,giH,ai); ai=MFMA(aP0,giL,ai);
#pragma unroll
        for (int ks=0;ks<4;++ks){
          bf16x8 bh=*(const bf16x8*)(ghH+ks*32);
          bf16x8 bl=*(const bf16x8*)(ghL+ks*32);
          ah=MFMA(aHi[ks],bh,ah); ah=MFMA(aLo[ks],bh,ah); ah=MFMA(aHi[ks],bl,ah);
        }
#pragma unroll
        for (int r=0;r<4;++r){ int m=quad*4+r; comb[m*388+gcol]=ai[r]+c1F[i]; nbuf[m*132+gcol-256]=ah[r]+c1N[i]; }
      }
    }
    __syncthreads();
    // ---- gates1 -> h1 ----
#pragma unroll
    for (int e=0;e<8;++e){
      int j=gj0+e;
      float r = sigm_(comb[gm*388+j]);
      float z = sigm_(comb[gm*388+128+j]);
      float n = tanh_(comb[gm*388+256+j] + r*nbuf[gm*132+j]);
      float hold = (float)h1Hi[gm*136+j] + (float)h1Lo[gm*136+j];
      float hnew = fin_((1.f-z)*n + z*hold);
      bf16 hi=(bf16)hnew;
      h1Hi[gm*136+j]=hi; h1Lo[gm*136+j]=(bf16)(hnew-(float)hi);
    }
    __syncthreads();
    // ---- cell2 preacts: gi = h1new@W1i^T, gh = h2@W1h^T (both K=128) ----
#pragma unroll
    for (int ks=0;ks<4;++ks){
      aHi[ks] = *(const bf16x8*)&h1Hi[lh*136+ks*32+quad*8];
      aLo[ks] = *(const bf16x8*)&h1Lo[lh*136+ks*32+quad*8];
    }
    bf16x8 a2Hi[4], a2Lo[4];
#pragma unroll
    for (int ks=0;ks<4;++ks){
      a2Hi[ks] = *(const bf16x8*)&h2Hi[lh*136+ks*32+quad*8];
      a2Lo[ks] = *(const bf16x8*)&h2Lo[lh*136+ks*32+quad*8];
    }
#pragma unroll
    for (int i=0;i<6;++i){
      int g0=wave*96+i*16, gcol=g0+lh;
      const bf16* giH = W1iH + (size_t)gcol*128 + quad*8;
      const bf16* giL = W1iL + (size_t)gcol*128 + quad*8;
      const bf16* ghH = W1hH + (size_t)gcol*128 + quad*8;
      const bf16* ghL = W1hL + (size_t)gcol*128 + quad*8;
      if (g0<256){
        f32x4 acc={0.f,0.f,0.f,0.f};
#pragma unroll
        for (int ks=0;ks<4;++ks){
          bf16x8 bh=*(const bf16x8*)(giH+ks*32);
          bf16x8 bl=*(const bf16x8*)(giL+ks*32);
          acc=MFMA(aHi[ks],bh,acc); acc=MFMA(aLo[ks],bh,acc); acc=MFMA(aHi[ks],bl,acc);
        }
#pragma unroll
        for (int ks=0;ks<4;++ks){
          bf16x8 bh=*(const bf16x8*)(ghH+ks*32);
          bf16x8 bl=*(const bf16x8*)(ghL+ks*32);
          acc=MFMA(a2Hi[ks],bh,acc); acc=MFMA(a2Lo[ks],bh,acc); acc=MFMA(a2Hi[ks],bl,acc);
        }
#pragma unroll
        for (int r=0;r<4;++r) comb[(quad*4+r)*388+gcol]=acc[r]+c2F[i];
      } else {
        f32x4 ai={0.f,0.f,0.f,0.f}, ah={0.f,0.f,0.f,0.f};
#pragma unroll
        for (int ks=0;ks<4;++ks){
          bf16x8 bh=*(const bf16x8*)(giH+ks*32);
          bf16x8 bl=*(const bf16x8*)(giL+ks*32);
          ai=MFMA(aHi[ks],bh,ai); ai=MFMA(aLo[ks],bh,ai); ai=MFMA(aHi[ks],bl,ai);
        }
#pragma unroll
        for (int ks=0;ks<4;++ks){
          bf16x8 bh=*(const bf16x8*)(ghH+ks*32);
          bf16x8 bl=*(const bf16x8*)(ghL+ks*32);
          ah=MFMA(a2Hi[ks],bh,ah); ah=MFMA(a2Lo[ks],bh,ah); ah=MFMA(a2Hi[ks],bl,ah);
        }
#pragma unroll
        for (int r=0;r<4;++r){ int m=quad*4+r; comb[m*388+gcol]=ai[r]+c2F[i]; nbuf[m*132+gcol-256]=ah[r]+c2N[i]; }
      }
    }
    __syncthreads();
    // ---- gates2 -> h2 ----
#pragma unroll
    for (int e=0;e<8;++e){
      int j=gj0+e;
      float r = sigm_(comb[gm*388+j]);
      float z = sigm_(comb[gm*388+128+j]);
      float n = tanh_(comb[gm*388+256+j] + r*nbuf[gm*132+j]);
      float hold = (float)h2Hi[gm*136+j] + (float)h2Lo[gm*136+j];
      float hnew = fin_((1.f-z)*n + z*hold);
      bf16 hi=(bf16)hnew;
      h2Hi[gm*136+j]=hi; h2Lo[gm*136+j]=(bf16)(hnew-(float)hi);
    }
    __syncthreads();
    // ---- output projection: pred = h2@Wo^T + bout (waves 0,1) ----
    if (wave<2){
      bf16x8 oHi[4], oLo[4];
#pragma unroll
      for (int ks=0;ks<4;++ks){
        oHi[ks] = *(const bf16x8*)&h2Hi[lh*136+ks*32+quad*8];
        oLo[ks] = *(const bf16x8*)&h2Lo[lh*136+ks*32+quad*8];
      }
      int gcol = wave*16+lh;
      const bf16* wH = WoH + (size_t)gcol*128 + quad*8;
      const bf16* wL = WoL + (size_t)gcol*128 + quad*8;
      f32x4 acc={0.f,0.f,0.f,0.f};
#pragma unroll
      for (int ks=0;ks<4;++ks){
        bf16x8 bh=*(const bf16x8*)(wH+ks*32);
        bf16x8 bl=*(const bf16x8*)(wL+ks*32);
        acc=MFMA(oHi[ks],bh,acc); acc=MFMA(oLo[ks],bh,acc); acc=MFMA(oHi[ks],bl,acc);
      }
#pragma unroll
      for (int r=0;r<4;++r){
        int m=quad*4+r;
        float pv = fin_(acc[r]+bo);
        rec[((size_t)(b0+m)*512 + t)*32 + gcol] = pv;
        bf16 hi=(bf16)pv;
        pHi[m*40+gcol]=hi; pLo[m*40+gcol]=(bf16)(pv-(float)hi);
      }
    }
    __syncthreads();
  }
}

// ---------------------------------------------------------------------------
extern "C" void kernel_launch(void* const* d_in, const int* in_sizes, int n_in,
                              void* d_out, int out_size, void* d_ws, size_t ws_size,
                              hipStream_t stream)
{
  const float* x       = (const float*)d_in[0];
  const int*   lengths = (const int*)d_in[1];
  const float* eps     = (const float*)d_in[2];
  const float* eWih0   = (const float*)d_in[3];   // [2,384,32]
  const float* eWhh0   = (const float*)d_in[4];   // [2,384,128]
  const float* ebih0   = (const float*)d_in[5];   // [2,384]
  const float* ebhh0   = (const float*)d_in[6];
  const float* eWih12  = (const float*)d_in[7];   // [2,2,384,256]
  const float* eWhh12  = (const float*)d_in[8];   // [2,2,384,128]
  const float* ebih12  = (const float*)d_in[9];   // [2,2,384]
  const float* ebhh12  = (const float*)d_in[10];
  const float* dWih0   = (const float*)d_in[11];
  const float* dWhh0   = (const float*)d_in[12];
  const float* dbih0   = (const float*)d_in[13];
  const float* dbhh0   = (const float*)d_in[14];
  const float* dWih1   = (const float*)d_in[15];
  const float* dWhh1   = (const float*)d_in[16];
  const float* dbih1   = (const float*)d_in[17];
  const float* dbhh1   = (const float*)d_in[18];
  const float* Wm      = (const float*)d_in[19];
  const float* bm      = (const float*)d_in[20];
  const float* Wl      = (const float*)d_in[21];
  const float* bl      = (const float*)d_in[22];
  const float* Wz      = (const float*)d_in[23];
  const float* bz      = (const float*)d_in[24];
  const float* Wo      = (const float*)d_in[25];
  const float* bo      = (const float*)d_in[26];

  // ws layout: [0,4M) bf16 hi/lo weight planes; [4M,68M) seqA; [68M,132M) seqB.
  // hF/hB/hInit fp32 (384 KiB) overlay seqA (dead after enc1 reads it).
  char* ws = (char*)d_ws;
  bf16* P     = (bf16*)ws;
  bf16* seqA  = (bf16*)(ws + (size_t)(4<<20));
  bf16* seqB  = (bf16*)(ws + (size_t)(68<<20));
  float* hF    = (float*)seqA;
  float* hB    = hF + 256*128;
  float* hInit = hB + 256*128;

  // plane offsets (elements): [hi | lo] per job
  const size_t O_eWih0  = 0;        // n 24576
  const size_t O_eWhh0  = 49152;    // n 98304
  const size_t O_eWih12 = 245760;   // n 393216
  const size_t O_eWhh12 = 1032192;  // n 196608
  const size_t O_dWih0  = 1425408;  // n 12288
  const size_t O_dWhh0  = 1449984;  // n 49152
  const size_t O_dWih1  = 1548288;  // n 49152
  const size_t O_dWhh1  = 1646592;  // n 49152
  const size_t O_Wout   = 1744896;  // n 4096

  float* out   = (float*)d_out;
  float* rec   = out;                      // [256,512,32]
  float* omean = out + (size_t)4194304;    // [256,32]
  float* ologv = omean + 8192;             // [256,32]

  // zero seq buffers (reference zero-pads invalid positions; consuming layer
  // reads them). 128 MiB starting at +4M.
  size_t zoff = (size_t)(4<<20);
  size_t zbytes = (size_t)(128<<20);
  if (zoff + zbytes > ws_size) zbytes = (ws_size > zoff)? ws_size - zoff : 0;
  hipMemsetAsync(ws + zoff, 0, zbytes, stream);

  // weight prep
  PrepJobs J;
  const float* srcs[9] = {eWih0, eWhh0, eWih12, eWhh12, dWih0, dWhh0, dWih1, dWhh1, Wo};
  const size_t offs[9] = {O_eWih0,O_eWhh0,O_eWih12,O_eWhh12,O_dWih0,O_dWhh0,O_dWih1,O_dWhh1,O_Wout};
  const int    ns[9]   = {24576, 98304, 393216, 196608, 12288, 49152, 49152, 49152, 4096};
  for (int j=0;j<9;++j){ J.src[j]=srcs[j]; J.hi[j]=P+offs[j]; J.lo[j]=P+offs[j]+ns[j]; J.n[j]=ns[j]; }
  prep_w<<<256, 256, 0, stream>>>(J);

  dim3 blk(256);

  // encoder layer 0 (x fp32, K=32)
  enc_rec<32,true><<<32, blk, 0, stream>>>(x, seqA,
      P+O_eWih0, P+O_eWih0+24576, P+O_eWhh0, P+O_eWhh0+98304,
      ebih0, ebhh0, lengths, nullptr, nullptr);
  // encoder layer 1 (seqA bf16, K=256)
  enc_rec<256,false><<<32, blk, 0, stream>>>(seqA, seqB,
      P+O_eWih12, P+O_eWih12+393216, P+O_eWhh12, P+O_eWhh12+196608,
      ebih12, ebhh12, lengths, nullptr, nullptr);
  // encoder layer 2 (seqB, K=256; final hidden only -> hF/hB in dead seqA)
  enc_rec<256,false><<<32, blk, 0, stream>>>(seqB, nullptr,
      P+O_eWih12+196608, P+O_eWih12+393216+196608,
      P+O_eWhh12+98304,  P+O_eWhh12+196608+98304,
      ebih12+768, ebhh12+768, lengths, hF, hB);
  // latent (all fp32)
  latent_k<<<256, 64, 0, stream>>>(hF, hB, eps, Wm, bm, Wl, bl, Wz, bz,
                                   omean, ologv, hInit);
  // decoder
  dec_rec<<<16, blk, 0, stream>>>(hInit,
      P+O_dWih0, P+O_dWih0+12288, P+O_dWhh0, P+O_dWhh0+49152,
      P+O_dWih1, P+O_dWih1+49152, P+O_dWhh1, P+O_dWhh1+49152,
      P+O_Wout,  P+O_Wout+4096,
      dbih0, dbhh0, dbih1, dbhh1, bo, rec);
}

// Round 5
// 29455.893 us; speedup vs baseline: 1.0828x; 1.0828x over previous
//
#include <hip/hip_runtime.h>
#include <hip/hip_bf16.h>

// VRAE forward on gfx950. FP32 I/O; MFMA via bf16 hi/lo planes (~fp32 accuracy).
// R5: latency attack. 768-thread blocks (12 waves, 3/SIMD) -> each wave owns 2 gate
// tiles (was 6), 3-way wave co-scheduling hides MFMA dep-chains + L2 weight-load
// latency. Encoder input is LDS-staged (double buffer) by the 8 non-gate waves
// during the previous gate phase, removing 12x-redundant global A-loads from the
// critical path. All arithmetic order preserved -> output bitwise identical to R4
// (absmax 0.043). Known next bottleneck: per-step weight streaming from L2
// (~600KB/step/CU ~= 3.9us floor) -> R6 candidate: weight-resident multi-block.

typedef __bf16 bf16;
typedef __bf16 bf16x8 __attribute__((ext_vector_type(8)));
typedef float f32x4 __attribute__((ext_vector_type(4)));

#define MFMA(a,b,c) __builtin_amdgcn_mfma_f32_16x16x32_bf16((a),(b),(c),0,0,0)

__device__ __forceinline__ float sigm_(float x){ return 1.f/(1.f+__expf(-x)); }
__device__ __forceinline__ float tanh_(float x){
  x = fminf(15.f, fmaxf(-15.f, x));
  float e = __expf(2.f*x);
  return (e-1.f)/(e+1.f);
}
__device__ __forceinline__ float fin_(float v){ return (v - v == 0.0f) ? v : 0.0f; }

// ---------------------------------------------------------------------------
// Weight prep: fp32 -> bf16 hi/lo planes in ws.
// ---------------------------------------------------------------------------
struct PrepJobs {
  const float* src[9];
  bf16* hi[9];
  bf16* lo[9];
  int n[9];
};

__global__ void prep_w(PrepJobs J){
  const int stride = gridDim.x*blockDim.x;
  const int t0 = blockIdx.x*blockDim.x + threadIdx.x;
  for (int j=0;j<9;++j){
    const float* __restrict__ s = J.src[j];
    bf16* __restrict__ h = J.hi[j];
    bf16* __restrict__ l = J.lo[j];
    const int n = J.n[j];
    for (int i=t0;i<n;i+=stride){
      float v = fin_(s[i]);
      bf16 hh = (bf16)v;
      h[i] = hh;
      l[i] = (bf16)(v - (float)hh);
    }
  }
}

// ---------------------------------------------------------------------------
// Encoder recurrent kernel. grid=32: blockIdx>>4 = dir, blockIdx&15 = batch
// slice of 16. block=768 (12 waves); wave w owns gate tiles 2w,2w+1 (16 cols each).
// Input for step t+1 staged into LDS by waves 4..11 during gate phase of step t.
// ---------------------------------------------------------------------------
template<int KIN, bool F32IN>
__global__ __launch_bounds__(768)
void enc_rec(const void* __restrict__ seqIn_,  // [256,512,KIN] fp32|bf16
             bf16* __restrict__ seqOut,        // [256,512,256] or null
             const bf16* __restrict__ WihHi_, const bf16* __restrict__ WihLo_, // [2,384,KIN]
             const bf16* __restrict__ WhhHi_, const bf16* __restrict__ WhhLo_, // [2,384,128]
             const float* __restrict__ bih_, const float* __restrict__ bhh_,   // [2,384]
             const int* __restrict__ lengths,
             float* __restrict__ hFo, float* __restrict__ hBo)                 // [256,128] or null
{
  constexpr int NKS = KIN/32;
  constexpr int ISTR = (KIN==32)? 40 : 264;   // padded LDS row stride (elems)
  constexpr int PLANES = F32IN? 2 : 1;        // hi(+lo) staging planes
  const int tid = threadIdx.x;
  const int wave = tid>>6;
  const int lane = tid&63;
  const int lh = lane&15;
  const int quad = lane>>4;
  const int dir = blockIdx.x>>4;
  const int b0 = (blockIdx.x&15)*16;

  const bf16* __restrict__ WihHi = WihHi_ + (size_t)dir*384*KIN;
  const bf16* __restrict__ WihLo = WihLo_ + (size_t)dir*384*KIN;
  const bf16* __restrict__ WhhHi = WhhHi_ + (size_t)dir*384*128;
  const bf16* __restrict__ WhhLo = WhhLo_ + (size_t)dir*384*128;
  const float* __restrict__ bih = bih_ + dir*384;
  const float* __restrict__ bhh = bhh_ + dir*384;

  __shared__ float comb[16*388];   // fused r,z preacts (cols 0..255) + gi_n (256..383)
  __shared__ float nbuf[16*132];   // gh_n
  __shared__ bf16 hHi[16*136];
  __shared__ bf16 hLo[16*136];
  __shared__ bf16 inBuf[2*PLANES*16*ISTR];   // double-buffered input staging

  for (int i=tid;i<16*136;i+=768){ hHi[i]=(bf16)0.f; hLo[i]=(bf16)0.f; }

  const int gm = tid&15;
  const int gj0 = (tid>>4)*8;          // only meaningful for tid<256
  const int lenG = lengths[b0+gm];
  const int Tmax = lengths[b0];        // sorted desc -> slice max

  // staging thread identity (waves 4..11): 512 threads, each owns (row mS, col block)
  const int sIdx = (tid >= 256)? (tid-256) : 0;
  const int mS = sIdx>>5;
  const int lenS = lengths[b0+mS];

  float biasF[2], biasN[2];
#pragma unroll
  for (int i=0;i<2;++i){
    int g0 = (wave*2+i)*16, gcol = g0+lh;
    float bi = bih[gcol], bh = bhh[gcol];
    biasF[i] = (g0<256)? bi+bh : bi;
    biasN[i] = bh;
  }

  // pre-stage t=0 input
  if (tid >= 256){
    const int tt = 0;
    int tb = dir? (lenS-1-tt) : tt; tb = tb<0?0:tb;
    if constexpr (F32IN){
      const int c = sIdx&31;
      float v = ((const float*)seqIn_)[((size_t)(b0+mS)*512+tb)*32 + c];
      bf16 hh = (bf16)v;
      inBuf[(0*2+0)*16*ISTR + mS*ISTR + c] = hh;
      inBuf[(0*2+1)*16*ISTR + mS*ISTR + c] = (bf16)(v-(float)hh);
    } else {
      const int c0 = (sIdx&31)*8;
      bf16x8 v = *(const bf16x8*)((const bf16*)seqIn_ + ((size_t)(b0+mS)*512+tb)*256 + c0);
      *(bf16x8*)&inBuf[0*16*ISTR + mS*ISTR + c0] = v;
    }
  }
  __syncthreads();

  for (int t=0;t<Tmax;++t){
    const int bsel = t&1;
    const bf16* inH = &inBuf[(bsel*PLANES+0)*16*ISTR];
    const bf16* inL = &inBuf[(bsel*PLANES+(PLANES-1))*16*ISTR];

    // ---- A-fragments from LDS ----
    bf16x8 aInHi[NKS], aInLo[F32IN? NKS : 1];
#pragma unroll
    for (int ks=0;ks<NKS;++ks){
      aInHi[ks] = *(const bf16x8*)&inH[lh*ISTR + ks*32 + quad*8];
      if constexpr (F32IN) aInLo[ks] = *(const bf16x8*)&inL[lh*ISTR + ks*32 + quad*8];
    }
    bf16x8 aHi[4], aLo[4];
#pragma unroll
    for (int ks=0;ks<4;++ks){
      aHi[ks] = *(const bf16x8*)&hHi[lh*136 + ks*32 + quad*8];
      aLo[ks] = *(const bf16x8*)&hLo[lh*136 + ks*32 + quad*8];
    }

    // ---- MFMA phase: 2 gate tiles per wave ----
#pragma unroll
    for (int i=0;i<2;++i){
      const int g0 = (wave*2+i)*16;
      const int gcol = g0+lh;
      const bf16* bgiH = WihHi + (size_t)gcol*KIN + quad*8;
      const bf16* bgiL = WihLo + (size_t)gcol*KIN + quad*8;
      const bf16* bghH = WhhHi + (size_t)gcol*128 + quad*8;
      const bf16* bghL = WhhLo + (size_t)gcol*128 + quad*8;
      if (g0 < 256){   // r,z: gi+gh fused in one accumulator
        f32x4 acc = {0.f,0.f,0.f,0.f};
#pragma unroll
        for (int ks=0;ks<NKS;++ks){
          bf16x8 bh = *(const bf16x8*)(bgiH + ks*32);
          bf16x8 bl = *(const bf16x8*)(bgiL + ks*32);
          acc = MFMA(aInHi[ks], bh, acc);
          if constexpr (F32IN) acc = MFMA(aInLo[ks], bh, acc);
          acc = MFMA(aInHi[ks], bl, acc);
        }
#pragma unroll
        for (int ks=0;ks<4;++ks){
          bf16x8 bh = *(const bf16x8*)(bghH + ks*32);
          bf16x8 bl = *(const bf16x8*)(bghL + ks*32);
          acc = MFMA(aHi[ks], bh, acc);
          acc = MFMA(aLo[ks], bh, acc);
          acc = MFMA(aHi[ks], bl, acc);
        }
#pragma unroll
        for (int r=0;r<4;++r) comb[(quad*4+r)*388 + gcol] = acc[r] + biasF[i];
      } else {         // n: keep gi and gh separate (r scales gh_n only)
        f32x4 ai = {0.f,0.f,0.f,0.f}, ah = {0.f,0.f,0.f,0.f};
#pragma unroll
        for (int ks=0;ks<NKS;++ks){
          bf16x8 bh = *(const bf16x8*)(bgiH + ks*32);
          bf16x8 bl = *(const bf16x8*)(bgiL + ks*32);
          ai = MFMA(aInHi[ks], bh, ai);
          if constexpr (F32IN) ai = MFMA(aInLo[ks], bh, ai);
          ai = MFMA(aInHi[ks], bl, ai);
        }
#pragma unroll
        for (int ks=0;ks<4;++ks){
          bf16x8 bh = *(const bf16x8*)(bghH + ks*32);
          bf16x8 bl = *(const bf16x8*)(bghL + ks*32);
          ah = MFMA(aHi[ks], bh, ah);
          ah = MFMA(aLo[ks], bh, ah);
          ah = MFMA(aHi[ks], bl, ah);
        }
#pragma unroll
        for (int r=0;r<4;++r){
          int m = quad*4+r;
          comb[m*388 + gcol] = ai[r] + biasF[i];
          nbuf[m*132 + (gcol-256)] = ah[r] + biasN[i];
        }
      }
    }
    __syncthreads();

    // ---- gate phase (threads 0..255) + staging of step t+1 (threads 256..767) ----
    if (tid < 256){
      const bool valid = (t < lenG);
      bf16x8 ov;
#pragma unroll
      for (int e=0;e<8;++e){
        const int j = gj0+e;
        float r = sigm_(comb[gm*388 + j]);
        float z = sigm_(comb[gm*388 + 128 + j]);
        float n = tanh_(comb[gm*388 + 256 + j] + r*nbuf[gm*132 + j]);
        float hold = (float)hHi[gm*136+j] + (float)hLo[gm*136+j];
        float hnew = fin_((1.f-z)*n + z*hold);
        float hsel = valid? hnew : hold;
        bf16 hi = (bf16)hsel;
        hHi[gm*136+j] = hi;
        hLo[gm*136+j] = (bf16)(hsel - (float)hi);
        ov[e] = (bf16)hnew;
      }
      if (valid && seqOut){
        int tb = dir? (lenG-1-t) : t;
        *(bf16x8*)(seqOut + ((size_t)(b0+gm)*512 + tb)*256 + dir*128 + gj0) = ov;
      }
    } else if (t+1 < Tmax){
      const int tt = t+1;
      const int bs = tt&1;
      int tb = dir? (lenS-1-tt) : tt; tb = tb<0?0:tb;
      if constexpr (F32IN){
        const int c = sIdx&31;
        float v = ((const float*)seqIn_)[((size_t)(b0+mS)*512+tb)*32 + c];
        bf16 hh = (bf16)v;
        inBuf[(bs*2+0)*16*ISTR + mS*ISTR + c] = hh;
        inBuf[(bs*2+1)*16*ISTR + mS*ISTR + c] = (bf16)(v-(float)hh);
      } else {
        const int c0 = (sIdx&31)*8;
        bf16x8 v = *(const bf16x8*)((const bf16*)seqIn_ + ((size_t)(b0+mS)*512+tb)*256 + c0);
        *(bf16x8*)&inBuf[bs*16*ISTR + mS*ISTR + c0] = v;
      }
    }
    __syncthreads();
  }

  float* hout = dir? hBo : hFo;
  if (hout && tid < 256){
#pragma unroll
    for (int e=0;e<8;++e){
      int j = gj0+e;
      hout[(size_t)(b0+gm)*128 + j] = fin_((float)hHi[gm*136+j] + (float)hLo[gm*136+j]);
    }
  }
}

// ---------------------------------------------------------------------------
// Latent: mean/logvar/z/h_init. grid=256 (block per batch row), block=64. fp32.
// ---------------------------------------------------------------------------
__global__ void latent_k(const float* __restrict__ hF, const float* __restrict__ hB,
                         const float* __restrict__ eps,
                         const float* __restrict__ Wm, const float* __restrict__ bm,
                         const float* __restrict__ Wl, const float* __restrict__ bl,
                         const float* __restrict__ Wz, const float* __restrict__ bz,
                         float* __restrict__ out_mean, float* __restrict__ out_logvar,
                         float* __restrict__ hInit)
{
  const int b = blockIdx.x, tid = threadIdx.x;
  __shared__ float hc[256];
  __shared__ float mv[64];
  __shared__ float zz[32];
  for (int k=tid;k<256;k+=64) hc[k] = fin_((k<128)? hF[(size_t)b*128+k] : hB[(size_t)b*128+k-128]);
  __syncthreads();
  {
    const int i = tid & 31;
    const float* W = (tid<32)? Wm : Wl;
    float acc = (tid<32)? bm[i] : bl[i];
    for (int k=0;k<256;++k) acc += hc[k]*W[i*256+k];
    acc = fin_(acc);
    mv[tid] = acc;
    if (tid<32) out_mean[b*32+i] = acc;
    else        out_logvar[b*32+(tid-32)] = acc;
  }
  __syncthreads();
  if (tid<32) zz[tid] = fin_(mv[tid] + __expf(0.5f*mv[32+tid]) * eps[b*32+tid]);
  __syncthreads();
  for (int j=tid;j<128;j+=64){
    float a = bz[j];
    for (int k=0;k<32;++k) a += zz[k]*Wz[j*32+k];
    hInit[(size_t)b*128 + j] = tanh_(fin_(a));
  }
}

// ---------------------------------------------------------------------------
// Decoder: 2-layer GRU + output projection, autoregressive T=512.
// grid=16 (batch slices of 16), block=768 (12 waves); wave w owns gate tiles
// 2w,2w+1 in each cell phase. 5 phases per step.
// ---------------------------------------------------------------------------
__global__ __launch_bounds__(768)
void dec_rec(const float* __restrict__ hInit,
             const bf16* __restrict__ W0iH, const bf16* __restrict__ W0iL,  // [384,32]
             const bf16* __restrict__ W0hH, const bf16* __restrict__ W0hL,  // [384,128]
             const bf16* __restrict__ W1iH, const bf16* __restrict__ W1iL,  // [384,128]
             const bf16* __restrict__ W1hH, const bf16* __restrict__ W1hL,  // [384,128]
             const bf16* __restrict__ WoH,  const bf16* __restrict__ WoL,   // [32,128]
             const float* __restrict__ bih0, const float* __restrict__ bhh0,
             const float* __restrict__ bih1, const float* __restrict__ bhh1,
             const float* __restrict__ bout,
             float* __restrict__ rec)        // [256,512,32] (d_out)
{
  const int tid=threadIdx.x, wave=tid>>6, lane=tid&63, lh=lane&15, quad=lane>>4;
  const int b0 = blockIdx.x*16;
  const int gm = tid&15, gj0=(tid>>4)*8;     // gate mapping (tid<256 only)

  __shared__ float comb[16*388];
  __shared__ float nbuf[16*132];
  __shared__ bf16 h1Hi[16*136], h1Lo[16*136], h2Hi[16*136], h2Lo[16*136];
  __shared__ bf16 pHi[16*40], pLo[16*40];

  if (tid < 256){
#pragma unroll
    for (int e=0;e<8;++e){
      int j=gj0+e;
      float v = fin_(hInit[(size_t)(b0+gm)*128 + j]);
      bf16 hi=(bf16)v, lo=(bf16)(v-(float)hi);
      h1Hi[gm*136+j]=hi; h1Lo[gm*136+j]=lo;
      h2Hi[gm*136+j]=hi; h2Lo[gm*136+j]=lo;
    }
  }
  for (int i=tid;i<16*40;i+=768){ pHi[i]=(bf16)0.f; pLo[i]=(bf16)0.f; }

  float c1F[2], c1N[2], c2F[2], c2N[2];
  bf16x8 giH[2], giL[2];                 // hoisted cell1 gi weights (K=32)
#pragma unroll
  for (int i=0;i<2;++i){
    int g0=(wave*2+i)*16, gcol=g0+lh;
    c1F[i] = (g0<256)? bih0[gcol]+bhh0[gcol] : bih0[gcol];  c1N[i]=bhh0[gcol];
    c2F[i] = (g0<256)? bih1[gcol]+bhh1[gcol] : bih1[gcol];  c2N[i]=bhh1[gcol];
    giH[i] = *(const bf16x8*)(W0iH + (size_t)gcol*32 + quad*8);
    giL[i] = *(const bf16x8*)(W0iL + (size_t)gcol*32 + quad*8);
  }
  const float bo = (wave<2)? bout[wave*16+lh] : 0.f;
  __syncthreads();

  for (int t=0;t<512;++t){
    // ---- cell1 preacts: gi = pred@W0i^T (K=32), gh = h1@W0h^T (K=128) ----
    bf16x8 aP0 = *(const bf16x8*)&pHi[lh*40 + quad*8];
    bf16x8 aP1 = *(const bf16x8*)&pLo[lh*40 + quad*8];
    bf16x8 aHi[4], aLo[4];
#pragma unroll
    for (int ks=0;ks<4;++ks){
      aHi[ks] = *(const bf16x8*)&h1Hi[lh*136+ks*32+quad*8];
      aLo[ks] = *(const bf16x8*)&h1Lo[lh*136+ks*32+quad*8];
    }
#pragma unroll
    for (int i=0;i<2;++i){
      int g0=(wave*2+i)*16, gcol=g0+lh;
      const bf16* ghH = W0hH + (size_t)gcol*128 + quad*8;
      const bf16* ghL = W0hL + (size_t)gcol*128 + quad*8;
      if (g0<256){
        f32x4 acc={0.f,0.f,0.f,0.f};
        acc=MFMA(aP0,giH[i],acc); acc=MFMA(aP1,giH[i],acc); acc=MFMA(aP0,giL[i],acc);
#pragma unroll
        for (int ks=0;ks<4;++ks){
          bf16x8 bh=*(const bf16x8*)(ghH+ks*32);
          bf16x8 bl=*(const bf16x8*)(ghL+ks*32);
          acc=MFMA(aHi[ks],bh,acc); acc=MFMA(aLo[ks],bh,acc); acc=MFMA(aHi[ks],bl,acc);
        }
#pragma unroll
        for (int r=0;r<4;++r) comb[(quad*4+r)*388+gcol]=acc[r]+c1F[i];
      } else {
        f32x4 ai={0.f,0.f,0.f,0.f}, ah={0.f,0.f,0.f,0.f};
        ai=MFMA(aP0,giH[i],ai); ai=MFMA(aP1,giH[i],ai); ai=MFMA(aP0,giL[i],ai);
#pragma unroll
        for (int ks=0;ks<4;++ks){
          bf16x8 bh=*(const bf16x8*)(ghH+ks*32);
          bf16x8 bl=*(const bf16x8*)(ghL+ks*32);
          ah=MFMA(aHi[ks],bh,ah); ah=MFMA(aLo[ks],bh,ah); ah=MFMA(aHi[ks],bl,ah);
        }
#pragma unroll
        for (int r=0;r<4;++r){ int m=quad*4+r; comb[m*388+gcol]=ai[r]+c1F[i]; nbuf[m*132+gcol-256]=ah[r]+c1N[i]; }
      }
    }
    __syncthreads();
    // ---- gates1 -> h1 (threads 0..255) ----
    if (tid < 256){
#pragma unroll
      for (int e=0;e<8;++e){
        int j=gj0+e;
        float r = sigm_(comb[gm*388+j]);
        float z = sigm_(comb[gm*388+128+j]);
        float n = tanh_(comb[gm*388+256+j] + r*nbuf[gm*132+j]);
        float hold = (float)h1Hi[gm*136+j] + (float)h1Lo[gm*136+j];
        float hnew = fin_((1.f-z)*n + z*hold);
        bf16 hi=(bf16)hnew;
        h1Hi[gm*136+j]=hi; h1Lo[gm*136+j]=(bf16)(hnew-(float)hi);
      }
    }
    __syncthreads();
    // ---- cell2 preacts: gi = h1new@W1i^T, gh = h2@W1h^T (both K=128) ----
#pragma unroll
    for (int ks=0;ks<4;++ks){
      aHi[ks] = *(const bf16x8*)&h1Hi[lh*136+ks*32+quad*8];
      aLo[ks] = *(const bf16x8*)&h1Lo[lh*136+ks*32+quad*8];
    }
    bf16x8 a2Hi[4], a2Lo[4];
#pragma unroll
    for (int ks=0;ks<4;++ks){
      a2Hi[ks] = *(const bf16x8*)&h2Hi[lh*136+ks*32+quad*8];
      a2Lo[ks] = *(const bf16x8*)&h2Lo[lh*136+ks*32+quad*8];
    }
#pragma unroll
    for (int i=0;i<2;++i){
      int g0=(wave*2+i)*16, gcol=g0+lh;
      const bf16* gi1H = W1iH + (size_t)gcol*128 + quad*8;
      const bf16* gi1L = W1iL + (size_t)gcol*128 + quad*8;
      const bf16* gh1H = W1hH + (size_t)gcol*128 + quad*8;
      const bf16* gh1L = W1hL + (size_t)gcol*128 + quad*8;
      if (g0<256){
        f32x4 acc={0.f,0.f,0.f,0.f};
#pragma unroll
        for (int ks=0;ks<4;++ks){
          bf16x8 bh=*(const bf16x8*)(gi1H+ks*32);
          bf16x8 bl=*(const bf16x8*)(gi1L+ks*32);
          acc=MFMA(aHi[ks],bh,acc); acc=MFMA(aLo[ks],bh,acc); acc=MFMA(aHi[ks],bl,acc);
        }
#pragma unroll
        for (int ks=0;ks<4;++ks){
          bf16x8 bh=*(const bf16x8*)(gh1H+ks*32);
          bf16x8 bl=*(const bf16x8*)(gh1L+ks*32);
          acc=MFMA(a2Hi[ks],bh,acc); acc=MFMA(a2Lo[ks],bh,acc); acc=MFMA(a2Hi[ks],bl,acc);
        }
#pragma unroll
        for (int r=0;r<4;++r) comb[(quad*4+r)*388+gcol]=acc[r]+c2F[i];
      } else {
        f32x4 ai={0.f,0.f,0.f,0.f}, ah={0.f,0.f,0.f,0.f};
#pragma unroll
        for (int ks=0;ks<4;++ks){
          bf16x8 bh=*(const bf16x8*)(gi1H+ks*32);
          bf16x8 bl=*(const bf16x8*)(gi1L+ks*32);
          ai=MFMA(aHi[ks],bh,ai); ai=MFMA(aLo[ks],bh,ai); ai=MFMA(aHi[ks],bl,ai);
        }
#pragma unroll
        for (int ks=0;ks<4;++ks){
          bf16x8 bh=*(const bf16x8*)(gh1H+ks*32);
          bf16x8 bl=*(const bf16x8*)(gh1L+ks*32);
          ah=MFMA(a2Hi[ks],bh,ah); ah=MFMA(a2Lo[ks],bh,ah); ah=MFMA(a2Hi[ks],bl,ah);
        }
#pragma unroll
        for (int r=0;r<4;++r){ int m=quad*4+r; comb[m*388+gcol]=ai[r]+c2F[i]; nbuf[m*132+gcol-256]=ah[r]+c2N[i]; }
      }
    }
    __syncthreads();
    // ---- gates2 -> h2 (threads 0..255) ----
    if (tid < 256){
#pragma unroll
      for (int e=0;e<8;++e){
        int j=gj0+e;
        float r = sigm_(comb[gm*388+j]);
        float z = sigm_(comb[gm*388+128+j]);
        float n = tanh_(comb[gm*388+256+j] + r*nbuf[gm*132+j]);
        float hold = (float)h2Hi[gm*136+j] + (float)h2Lo[gm*136+j];
        float hnew = fin_((1.f-z)*n + z*hold);
        bf16 hi=(bf16)hnew;
        h2Hi[gm*136+j]=hi; h2Lo[gm*136+j]=(bf16)(hnew-(float)hi);
      }
    }
    __syncthreads();
    // ---- output projection: pred = h2@Wo^T + bout (waves 0,1) ----
    if (wave<2){
      bf16x8 oHi[4], oLo[4];
#pragma unroll
      for (int ks=0;ks<4;++ks){
        oHi[ks] = *(const bf16x8*)&h2Hi[lh*136+ks*32+quad*8];
        oLo[ks] = *(const bf16x8*)&h2Lo[lh*136+ks*32+quad*8];
      }
      int gcol = wave*16+lh;
      const bf16* wH = WoH + (size_t)gcol*128 + quad*8;
      const bf16* wL = WoL + (size_t)gcol*128 + quad*8;
      f32x4 acc={0.f,0.f,0.f,0.f};
#pragma unroll
      for (int ks=0;ks<4;++ks){
        bf16x8 bh=*(const bf16x8*)(wH+ks*32);
        bf16x8 bl=*(const bf16x8*)(wL+ks*32);
        acc=MFMA(oHi[ks],bh,acc); acc=MFMA(oLo[ks],bh,acc); acc=MFMA(oHi[ks],bl,acc);
      }
#pragma unroll
      for (int r=0;r<4;++r){
        int m=quad*4+r;
        float pv = fin_(acc[r]+bo);
        rec[((size_t)(b0+m)*512 + t)*32 + gcol] = pv;
        bf16 hi=(bf16)pv;
        pHi[m*40+gcol]=hi; pLo[m*40+gcol]=(bf16)(pv-(float)hi);
      }
    }
    __syncthreads();
  }
}

// ---------------------------------------------------------------------------
extern "C" void kernel_launch(void* const* d_in, const int* in_sizes, int n_in,
                              void* d_out, int out_size, void* d_ws, size_t ws_size,
                              hipStream_t stream)
{
  const float* x       = (const float*)d_in[0];
  const int*   lengths = (const int*)d_in[1];
  const float* eps     = (const float*)d_in[2];
  const float* eWih0   = (const float*)d_in[3];   // [2,384,32]
  const float* eWhh0   = (const float*)d_in[4];   // [2,384,128]
  const float* ebih0   = (const float*)d_in[5];   // [2,384]
  const float* ebhh0   = (const float*)d_in[6];
  const float* eWih12  = (const float*)d_in[7];   // [2,2,384,256]
  const float* eWhh12  = (const float*)d_in[8];   // [2,2,384,128]
  const float* ebih12  = (const float*)d_in[9];   // [2,2,384]
  const float* ebhh12  = (const float*)d_in[10];
  const float* dWih0   = (const float*)d_in[11];
  const float* dWhh0   = (const float*)d_in[12];
  const float* dbih0   = (const float*)d_in[13];
  const float* dbhh0   = (const float*)d_in[14];
  const float* dWih1   = (const float*)d_in[15];
  const float* dWhh1   = (const float*)d_in[16];
  const float* dbih1   = (const float*)d_in[17];
  const float* dbhh1   = (const float*)d_in[18];
  const float* Wm      = (const float*)d_in[19];
  const float* bm      = (const float*)d_in[20];
  const float* Wl      = (const float*)d_in[21];
  const float* bl      = (const float*)d_in[22];
  const float* Wz      = (const float*)d_in[23];
  const float* bz      = (const float*)d_in[24];
  const float* Wo      = (const float*)d_in[25];
  const float* bo      = (const float*)d_in[26];

  // ws layout: [0,4M) bf16 hi/lo weight planes; [4M,68M) seqA; [68M,132M) seqB.
  // hF/hB/hInit fp32 (384 KiB) overlay seqA (dead after enc1 reads it).
  char* ws = (char*)d_ws;
  bf16* P     = (bf16*)ws;
  bf16* seqA  = (bf16*)(ws + (size_t)(4<<20));
  bf16* seqB  = (bf16*)(ws + (size_t)(68<<20));
  float* hF    = (float*)seqA;
  float* hB    = hF + 256*128;
  float* hInit = hB + 256*128;

  // plane offsets (elements): [hi | lo] per job
  const size_t O_eWih0  = 0;        // n 24576
  const size_t O_eWhh0  = 49152;    // n 98304
  const size_t O_eWih12 = 245760;   // n 393216
  const size_t O_eWhh12 = 1032192;  // n 196608
  const size_t O_dWih0  = 1425408;  // n 12288
  const size_t O_dWhh0  = 1449984;  // n 49152
  const size_t O_dWih1  = 1548288;  // n 49152
  const size_t O_dWhh1  = 1646592;  // n 49152
  const size_t O_Wout   = 1744896;  // n 4096

  float* out   = (float*)d_out;
  float* rec   = out;                      // [256,512,32]
  float* omean = out + (size_t)4194304;    // [256,32]
  float* ologv = omean + 8192;             // [256,32]

  // zero seq buffers (invalid positions are read-then-masked by consumers)
  size_t zoff = (size_t)(4<<20);
  size_t zbytes = (size_t)(128<<20);
  if (zoff + zbytes > ws_size) zbytes = (ws_size > zoff)? ws_size - zoff : 0;
  hipMemsetAsync(ws + zoff, 0, zbytes, stream);

  // weight prep
  PrepJobs J;
  const float* srcs[9] = {eWih0, eWhh0, eWih12, eWhh12, dWih0, dWhh0, dWih1, dWhh1, Wo};
  const size_t offs[9] = {O_eWih0,O_eWhh0,O_eWih12,O_eWhh12,O_dWih0,O_dWhh0,O_dWih1,O_dWhh1,O_Wout};
  const int    ns[9]   = {24576, 98304, 393216, 196608, 12288, 49152, 49152, 49152, 4096};
  for (int j=0;j<9;++j){ J.src[j]=srcs[j]; J.hi[j]=P+offs[j]; J.lo[j]=P+offs[j]+ns[j]; J.n[j]=ns[j]; }
  prep_w<<<256, 256, 0, stream>>>(J);

  dim3 blk(768);

  // encoder layer 0 (x fp32, K=32)
  enc_rec<32,true><<<32, blk, 0, stream>>>(x, seqA,
      P+O_eWih0, P+O_eWih0+24576, P+O_eWhh0, P+O_eWhh0+98304,
      ebih0, ebhh0, lengths, nullptr, nullptr);
  // encoder layer 1 (seqA bf16, K=256)
  enc_rec<256,false><<<32, blk, 0, stream>>>(seqA, seqB,
      P+O_eWih12, P+O_eWih12+393216, P+O_eWhh12, P+O_eWhh12+196608,
      ebih12, ebhh12, lengths, nullptr, nullptr);
  // encoder layer 2 (seqB, K=256; final hidden only -> hF/hB in dead seqA)
  enc_rec<256,false><<<32, blk, 0, stream>>>(seqB, nullptr,
      P+O_eWih12+196608, P+O_eWih12+393216+196608,
      P+O_eWhh12+98304,  P+O_eWhh12+196608+98304,
      ebih12+768, ebhh12+768, lengths, hF, hB);
  // latent (all fp32)
  latent_k<<<256, 64, 0, stream>>>(hF, hB, eps, Wm, bm, Wl, bl, Wz, bz,
                                   omean, ologv, hInit);
  // decoder
  dec_rec<<<16, blk, 0, stream>>>(hInit,
      P+O_dWih0, P+O_dWih0+12288, P+O_dWhh0, P+O_dWhh0+49152,
      P+O_dWih1, P+O_dWih1+49152, P+O_dWhh1, P+O_dWhh1+49152,
      P+O_Wout,  P+O_Wout+4096,
      dbih0, dbhh0, dbih1, dbhh1, bo, rec);
}

// Round 6
// 10251.969 us; speedup vs baseline: 3.1110x; 2.8732x over previous
//
#include <hip/hip_runtime.h>
#include <hip/hip_bf16.h>

// VRAE forward on gfx950. FP32 I/O; MFMA via bf16 hi/lo planes (~fp32 accuracy).
// R6: weight-residency restructure. Wave w owns gate-tile triplet {w,8+w,16+w}
// (r,z,n of the same 16 hidden units) -> gates computed fully in-register on the
// MFMA accumulators (no comb/nbuf LDS). Encoder: Whh register-resident across all
// 512 steps (96 VGPR); Wih streamed once per 4 steps (burst gi for t+1..t+4 into
// register acc groups, x staged in LDS). Decoder: W0h+W1h resident (192 VGPR);
// only W0i/W1i/Wo streamed. 2 barriers/step (enc), 5 (dec). FP order per
// accumulator preserved vs R5 -> absmax should stay ~0.043.

typedef __bf16 bf16;
typedef __bf16 bf16x8 __attribute__((ext_vector_type(8)));
typedef float f32x4 __attribute__((ext_vector_type(4)));

#define MFMA(a,b,c) __builtin_amdgcn_mfma_f32_16x16x32_bf16((a),(b),(c),0,0,0)

__device__ __forceinline__ float sigm_(float x){ return 1.f/(1.f+__expf(-x)); }
__device__ __forceinline__ float tanh_(float x){
  x = fminf(15.f, fmaxf(-15.f, x));
  float e = __expf(2.f*x);
  return (e-1.f)/(e+1.f);
}
__device__ __forceinline__ float fin_(float v){ return (v - v == 0.0f) ? v : 0.0f; }

// ---------------------------------------------------------------------------
// Weight prep: fp32 -> bf16 hi/lo planes in ws.
// ---------------------------------------------------------------------------
struct PrepJobs {
  const float* src[9];
  bf16* hi[9];
  bf16* lo[9];
  int n[9];
};

__global__ void prep_w(PrepJobs J){
  const int stride = gridDim.x*blockDim.x;
  const int t0 = blockIdx.x*blockDim.x + threadIdx.x;
  for (int j=0;j<9;++j){
    const float* __restrict__ s = J.src[j];
    bf16* __restrict__ h = J.hi[j];
    bf16* __restrict__ l = J.lo[j];
    const int n = J.n[j];
    for (int i=t0;i<n;i+=stride){
      float v = fin_(s[i]);
      bf16 hh = (bf16)v;
      h[i] = hh;
      l[i] = (bf16)(v - (float)hh);
    }
  }
}

// ---------------------------------------------------------------------------
// Encoder recurrent kernel. grid=32: blockIdx>>4 = dir, blockIdx&15 = batch
// slice of 16. block=512 (8 waves). Wave w owns gate triplet {w,8+w,16+w}.
// Whh hi/lo register-resident; Wih swept once per 4 steps (gi burst).
// ---------------------------------------------------------------------------
template<int KIN, bool F32IN>
__global__ __launch_bounds__(512,2)
void enc_rec(const void* __restrict__ seqIn_,  // [256,512,KIN] fp32|bf16
             bf16* __restrict__ seqOut,        // [256,512,256] or null
             const bf16* __restrict__ WihHi_, const bf16* __restrict__ WihLo_, // [2,384,KIN]
             const bf16* __restrict__ WhhHi_, const bf16* __restrict__ WhhLo_, // [2,384,128]
             const float* __restrict__ bih_, const float* __restrict__ bhh_,   // [2,384]
             const int* __restrict__ lengths,
             float* __restrict__ hFo, float* __restrict__ hBo)                 // [256,128] or null
{
  constexpr int NKS  = KIN/32;
  constexpr int XSTR = F32IN ? 40 : 264;           // LDS x-row stride (elems)
  constexpr int XPL  = 16*XSTR;                    // one plane
  constexpr int XSLOT= (F32IN?2:1)*XPL;            // per step-slot (hi[,lo])
  const int tid = threadIdx.x;
  const int wave = tid>>6;
  const int lh   = tid&15;        // == lane&15 (A-row / C-col)
  const int quad = (tid>>4)&3;    // == lane>>4
  const int dir  = blockIdx.x>>4;
  const int b0   = (blockIdx.x&15)*16;

  const bf16* __restrict__ WihHi = WihHi_ + (size_t)dir*384*KIN;
  const bf16* __restrict__ WihLo = WihLo_ + (size_t)dir*384*KIN;
  const bf16* __restrict__ WhhHi = WhhHi_ + (size_t)dir*384*128;
  const bf16* __restrict__ WhhLo = WhhLo_ + (size_t)dir*384*128;
  const float* __restrict__ bih = bih_ + dir*384;
  const float* __restrict__ bhh = bhh_ + dir*384;

  __shared__ bf16 hHi[16*136], hLo[16*136];
  __shared__ bf16 xb[4*XSLOT];

  const int jc = wave*16 + lh;           // this lane's hidden-unit column
  const int cR = jc, cZ = 128+jc, cN = 256+jc;

  // ---- resident Whh hi/lo frags (loaded once; 24 frags = 96 VGPR) ----
  bf16x8 wRH[4],wRL[4],wZH[4],wZL[4],wNH[4],wNL[4];
#pragma unroll
  for (int ks=0;ks<4;++ks){
    const int o = ks*32 + quad*8;
    wRH[ks]=*(const bf16x8*)(WhhHi+(size_t)cR*128+o); wRL[ks]=*(const bf16x8*)(WhhLo+(size_t)cR*128+o);
    wZH[ks]=*(const bf16x8*)(WhhHi+(size_t)cZ*128+o); wZL[ks]=*(const bf16x8*)(WhhLo+(size_t)cZ*128+o);
    wNH[ks]=*(const bf16x8*)(WhhHi+(size_t)cN*128+o); wNL[ks]=*(const bf16x8*)(WhhLo+(size_t)cN*128+o);
  }
  const float bR  = bih[cR]+bhh[cR];
  const float bZc = bih[cZ]+bhh[cZ];
  const float bNi = bih[cN];
  const float bNh = bhh[cN];

  int lenRow[4];
#pragma unroll
  for (int r=0;r<4;++r) lenRow[r] = lengths[b0 + quad*4 + r];
  const int lenA = lengths[b0+lh];
  const int Tmax = lengths[b0];          // sorted desc -> slice max
  const int TT   = (Tmax+3)&~3;

  // seqOut-writer identity (tid<256): row, 8-col block
  const int wrow = (tid>>4)&15;
  const int wcol = (tid&15)*8;
  const int lenW = lengths[b0 + wrow];
  // staging identity (all 512 threads)
  const int srow = tid>>5;               // 0..15
  const int scol = tid&31;               // col block
  const int lenS = lengths[b0 + srow];

  for (int i=tid;i<16*136;i+=512){ hHi[i]=(bf16)0.f; hLo[i]=(bf16)0.f; }

  auto stage = [&](int slot, int sabs){
    int tb = dir ? (lenS-1-sabs) : sabs;
    tb = tb<0 ? 0 : (tb>511 ? 511 : tb);
    if constexpr (F32IN){
      float v = ((const float*)seqIn_)[((size_t)(b0+srow)*512+tb)*32 + scol];
      bf16 hh=(bf16)v;
      xb[slot*XSLOT + srow*XSTR + scol] = hh;
      xb[slot*XSLOT + XPL + srow*XSTR + scol] = (bf16)(v-(float)hh);
    } else {
      bf16x8 v = *(const bf16x8*)((const bf16*)seqIn_ + ((size_t)(b0+srow)*512+tb)*256 + scol*8);
      *(bf16x8*)&xb[slot*XSLOT + srow*XSTR + scol*8] = v;
    }
  };
  // prologue: stage x for steps 1..4 (burst at window 0 covers them)
#pragma unroll
  for (int s=0;s<4;++s) stage(s, 1+s);

  // gi acc groups (12 f32x4 = 48 VGPR)
  f32x4 accR[4], accZ[4], giN[4];
#pragma unroll
  for (int s=0;s<4;++s){
    accR[s]=(f32x4){0.f,0.f,0.f,0.f}; accZ[s]=(f32x4){0.f,0.f,0.f,0.f}; giN[s]=(f32x4){0.f,0.f,0.f,0.f};
  }

  // prologue: gi(0) -> slot 3 (A-frags direct from global)
  {
    int tb0 = dir ? (lenA-1) : 0; tb0 = tb0<0?0:tb0;
#pragma unroll
    for (int ks=0;ks<NKS;++ks){
      const int o = ks*32 + quad*8;
      bf16x8 axH, axL;
      if constexpr (F32IN){
        const float* ap = (const float*)seqIn_ + ((size_t)(b0+lh)*512+tb0)*KIN + o;
#pragma unroll
        for (int e=0;e<8;++e){ float v=ap[e]; bf16 hh=(bf16)v; axH[e]=hh; axL[e]=(bf16)(v-(float)hh); }
      } else {
        axH = *(const bf16x8*)((const bf16*)seqIn_ + ((size_t)(b0+lh)*512+tb0)*KIN + o);
      }
      bf16x8 bH, bL;
      bH=*(const bf16x8*)(WihHi+(size_t)cR*KIN+o); bL=*(const bf16x8*)(WihLo+(size_t)cR*KIN+o);
      accR[3]=MFMA(axH,bH,accR[3]); if constexpr(F32IN) accR[3]=MFMA(axL,bH,accR[3]); accR[3]=MFMA(axH,bL,accR[3]);
      bH=*(const bf16x8*)(WihHi+(size_t)cZ*KIN+o); bL=*(const bf16x8*)(WihLo+(size_t)cZ*KIN+o);
      accZ[3]=MFMA(axH,bH,accZ[3]); if constexpr(F32IN) accZ[3]=MFMA(axL,bH,accZ[3]); accZ[3]=MFMA(axH,bL,accZ[3]);
      bH=*(const bf16x8*)(WihHi+(size_t)cN*KIN+o); bL=*(const bf16x8*)(WihLo+(size_t)cN*KIN+o);
      giN[3]=MFMA(axH,bH,giN[3]);  if constexpr(F32IN) giN[3]=MFMA(axL,bH,giN[3]);  giN[3]=MFMA(axH,bL,giN[3]);
    }
  }
  __syncthreads();

  for (int t4=0; t4<TT; t4+=4){
#pragma unroll
    for (int p=0;p<4;++p){
      const int t = t4 + p;
      const int s = (p+3)&3;     // gi slot consumed this window
      // ---- Phase A ----
      // seqOut writer for step t-1 (reads h(t-1) from LDS, coalesced b128)
      if (seqOut && tid<256 && t>0 && (t-1)<lenW){
        const int tp = t-1;
        const int tb = dir ? (lenW-1-tp) : tp;
        bf16x8 v = *(const bf16x8*)&hHi[wrow*136 + wcol];
        *(bf16x8*)(seqOut + ((size_t)(b0+wrow)*512 + tb)*256 + dir*128 + wcol) = v;
      }
      // rec: gh MFMAs (resident Whh) appended onto gi accs
      f32x4 gN = {0.f,0.f,0.f,0.f};
#pragma unroll
      for (int ks=0;ks<4;++ks){
        bf16x8 aH = *(const bf16x8*)&hHi[lh*136 + ks*32 + quad*8];
        bf16x8 aL = *(const bf16x8*)&hLo[lh*136 + ks*32 + quad*8];
        accR[s]=MFMA(aH,wRH[ks],accR[s]); accR[s]=MFMA(aL,wRH[ks],accR[s]); accR[s]=MFMA(aH,wRL[ks],accR[s]);
        accZ[s]=MFMA(aH,wZH[ks],accZ[s]); accZ[s]=MFMA(aL,wZH[ks],accZ[s]); accZ[s]=MFMA(aH,wZL[ks],accZ[s]);
        gN     =MFMA(aH,wNH[ks],gN);      gN     =MFMA(aL,wNH[ks],gN);      gN     =MFMA(aH,wNL[ks],gN);
      }
      // gates (in-register, C-layout: rows quad*4+r, col jc)
      float hsel[4];
#pragma unroll
      for (int r=0;r<4;++r){
        const int m = quad*4 + r;
        float rr = sigm_(accR[s][r] + bR);
        float zz = sigm_(accZ[s][r] + bZc);
        float nn = tanh_(giN[s][r] + bNi + rr*(gN[r] + bNh));
        float hold = (float)hHi[m*136+jc] + (float)hLo[m*136+jc];
        float hnew = fin_((1.f-zz)*nn + zz*hold);
        hsel[r] = (t < lenRow[r]) ? hnew : hold;
      }
      // burst: gi for steps t+1..t+4 (Wih swept once; x from LDS)
      if (p==0){
#pragma unroll
        for (int s2=0;s2<4;++s2){
          accR[s2]=(f32x4){0.f,0.f,0.f,0.f}; accZ[s2]=(f32x4){0.f,0.f,0.f,0.f}; giN[s2]=(f32x4){0.f,0.f,0.f,0.f};
        }
#pragma unroll
        for (int ks=0;ks<NKS;++ks){
          const int o = ks*32 + quad*8;
          bf16x8 axH[4], axL[F32IN?4:1];
#pragma unroll
          for (int s2=0;s2<4;++s2){
            axH[s2] = *(const bf16x8*)&xb[s2*XSLOT + lh*XSTR + o];
            if constexpr (F32IN) axL[s2] = *(const bf16x8*)&xb[s2*XSLOT + XPL + lh*XSTR + o];
          }
          bf16x8 bH, bL;
          bH=*(const bf16x8*)(WihHi+(size_t)cR*KIN+o); bL=*(const bf16x8*)(WihLo+(size_t)cR*KIN+o);
#pragma unroll
          for (int s2=0;s2<4;++s2){
            accR[s2]=MFMA(axH[s2],bH,accR[s2]);
            if constexpr(F32IN) accR[s2]=MFMA(axL[s2],bH,accR[s2]);
            accR[s2]=MFMA(axH[s2],bL,accR[s2]);
          }
          bH=*(const bf16x8*)(WihHi+(size_t)cZ*KIN+o); bL=*(const bf16x8*)(WihLo+(size_t)cZ*KIN+o);
#pragma unroll
          for (int s2=0;s2<4;++s2){
            accZ[s2]=MFMA(axH[s2],bH,accZ[s2]);
            if constexpr(F32IN) accZ[s2]=MFMA(axL[s2],bH,accZ[s2]);
            accZ[s2]=MFMA(axH[s2],bL,accZ[s2]);
          }
          bH=*(const bf16x8*)(WihHi+(size_t)cN*KIN+o); bL=*(const bf16x8*)(WihLo+(size_t)cN*KIN+o);
#pragma unroll
          for (int s2=0;s2<4;++s2){
            giN[s2]=MFMA(axH[s2],bH,giN[s2]);
            if constexpr(F32IN) giN[s2]=MFMA(axL[s2],bH,giN[s2]);
            giN[s2]=MFMA(axH[s2],bL,giN[s2]);
          }
        }
      }
      __syncthreads();     // B1: h reads (A-frags, writer, hold) done
      // ---- Phase B ----
#pragma unroll
      for (int r=0;r<4;++r){
        const int m = quad*4 + r;
        bf16 hi = (bf16)hsel[r];
        hHi[m*136+jc] = hi;
        hLo[m*136+jc] = (bf16)(hsel[r]-(float)hi);
      }
      if      (p==1){ stage(0, t4+5); stage(1, t4+6); }
      else if (p==2){ stage(2, t4+7); }
      else if (p==3){ stage(3, t4+8); }
      __syncthreads();     // B2: h(t) + staged x visible
    }
  }
  // epilogue: seqOut for step TT-1
  if (seqOut && tid<256 && (TT-1)<lenW){
    const int tb = dir ? (lenW-1-(TT-1)) : (TT-1);
    bf16x8 v = *(const bf16x8*)&hHi[wrow*136 + wcol];
    *(bf16x8*)(seqOut + ((size_t)(b0+wrow)*512 + tb)*256 + dir*128 + wcol) = v;
  }
  float* hout = dir ? hBo : hFo;
  if (hout && tid<256){
#pragma unroll
    for (int e=0;e<8;++e){
      const int j = wcol+e;
      hout[(size_t)(b0+wrow)*128 + j] = fin_((float)hHi[wrow*136+j] + (float)hLo[wrow*136+j]);
    }
  }
}

// ---------------------------------------------------------------------------
// Latent: mean/logvar/z/h_init. grid=256 (block per batch row), block=64. fp32.
// ---------------------------------------------------------------------------
__global__ void latent_k(const float* __restrict__ hF, const float* __restrict__ hB,
                         const float* __restrict__ eps,
                         const float* __restrict__ Wm, const float* __restrict__ bm,
                         const float* __restrict__ Wl, const float* __restrict__ bl,
                         const float* __restrict__ Wz, const float* __restrict__ bz,
                         float* __restrict__ out_mean, float* __restrict__ out_logvar,
                         float* __restrict__ hInit)
{
  const int b = blockIdx.x, tid = threadIdx.x;
  __shared__ float hc[256];
  __shared__ float mv[64];
  __shared__ float zz[32];
  for (int k=tid;k<256;k+=64) hc[k] = fin_((k<128)? hF[(size_t)b*128+k] : hB[(size_t)b*128+k-128]);
  __syncthreads();
  {
    const int i = tid & 31;
    const float* W = (tid<32)? Wm : Wl;
    float acc = (tid<32)? bm[i] : bl[i];
    for (int k=0;k<256;++k) acc += hc[k]*W[i*256+k];
    acc = fin_(acc);
    mv[tid] = acc;
    if (tid<32) out_mean[b*32+i] = acc;
    else        out_logvar[b*32+(tid-32)] = acc;
  }
  __syncthreads();
  if (tid<32) zz[tid] = fin_(mv[tid] + __expf(0.5f*mv[32+tid]) * eps[b*32+tid]);
  __syncthreads();
  for (int j=tid;j<128;j+=64){
    float a = bz[j];
    for (int k=0;k<32;++k) a += zz[k]*Wz[j*32+k];
    hInit[(size_t)b*128 + j] = tanh_(fin_(a));
  }
}

// ---------------------------------------------------------------------------
// Decoder: 2-layer GRU + out-proj, T=512. grid=16, block=512 (8 waves).
// Wave w owns gate triplet {w,8+w,16+w} for both cells; W0h+W1h resident.
// ---------------------------------------------------------------------------
__global__ __launch_bounds__(512,2)
void dec_rec(const float* __restrict__ hInit,
             const bf16* __restrict__ W0iH, const bf16* __restrict__ W0iL,  // [384,32]
             const bf16* __restrict__ W0hH, const bf16* __restrict__ W0hL,  // [384,128]
             const bf16* __restrict__ W1iH, const bf16* __restrict__ W1iL,  // [384,128]
             const bf16* __restrict__ W1hH, const bf16* __restrict__ W1hL,  // [384,128]
             const bf16* __restrict__ WoH,  const bf16* __restrict__ WoL,   // [32,128]
             const float* __restrict__ bih0, const float* __restrict__ bhh0,
             const float* __restrict__ bih1, const float* __restrict__ bhh1,
             const float* __restrict__ bout,
             float* __restrict__ rec)        // [256,512,32]
{
  const int tid = threadIdx.x;
  const int wave = tid>>6;
  const int lh   = tid&15;
  const int quad = (tid>>4)&3;
  const int b0 = blockIdx.x*16;
  const int jc = wave*16 + lh;
  const int cR = jc, cZ = 128+jc, cN = 256+jc;

  __shared__ bf16 h1H[16*136], h1L[16*136], h2H[16*136], h2L[16*136];
  __shared__ bf16 pH[16*40], pL[16*40];

  // resident W0h, W1h hi/lo (48 frags = 192 VGPR)
  bf16x8 a0RH[4],a0RL[4],a0ZH[4],a0ZL[4],a0NH[4],a0NL[4];
  bf16x8 a1RH[4],a1RL[4],a1ZH[4],a1ZL[4],a1NH[4],a1NL[4];
#pragma unroll
  for (int ks=0;ks<4;++ks){
    const int o = ks*32 + quad*8;
    a0RH[ks]=*(const bf16x8*)(W0hH+(size_t)cR*128+o); a0RL[ks]=*(const bf16x8*)(W0hL+(size_t)cR*128+o);
    a0ZH[ks]=*(const bf16x8*)(W0hH+(size_t)cZ*128+o); a0ZL[ks]=*(const bf16x8*)(W0hL+(size_t)cZ*128+o);
    a0NH[ks]=*(const bf16x8*)(W0hH+(size_t)cN*128+o); a0NL[ks]=*(const bf16x8*)(W0hL+(size_t)cN*128+o);
    a1RH[ks]=*(const bf16x8*)(W1hH+(size_t)cR*128+o); a1RL[ks]=*(const bf16x8*)(W1hL+(size_t)cR*128+o);
    a1ZH[ks]=*(const bf16x8*)(W1hH+(size_t)cZ*128+o); a1ZL[ks]=*(const bf16x8*)(W1hL+(size_t)cZ*128+o);
    a1NH[ks]=*(const bf16x8*)(W1hH+(size_t)cN*128+o); a1NL[ks]=*(const bf16x8*)(W1hL+(size_t)cN*128+o);
  }
  const float b1R = bih0[cR]+bhh0[cR], b1Z = bih0[cZ]+bhh0[cZ], b1Ni = bih0[cN], b1Nh = bhh0[cN];
  const float b2R = bih1[cR]+bhh1[cR], b2Z = bih1[cZ]+bhh1[cZ], b2Ni = bih1[cN], b2Nh = bhh1[cN];
  const float bo = (wave<2) ? bout[wave*16+lh] : 0.f;

  // init h1,h2 from hInit; pred = 0
  if (tid < 256){
    const int row = (tid>>4)&15;
    const int c0  = (tid&15)*8;
#pragma unroll
    for (int e=0;e<8;++e){
      const int j = c0+e;
      float v = fin_(hInit[(size_t)(b0+row)*128 + j]);
      bf16 hi=(bf16)v, lo=(bf16)(v-(float)hi);
      h1H[row*136+j]=hi; h1L[row*136+j]=lo;
      h2H[row*136+j]=hi; h2L[row*136+j]=lo;
    }
  }
  for (int i=tid;i<16*40;i+=512){ pH[i]=(bf16)0.f; pL[i]=(bf16)0.f; }
  __syncthreads();

  for (int t=0;t<512;++t){
    // ---- cell1: gi = pred@W0i (K=32, streamed), gh = h1@W0h (resident) ----
    f32x4 xR={0.f,0.f,0.f,0.f}, xZ={0.f,0.f,0.f,0.f}, xNi={0.f,0.f,0.f,0.f}, xNh={0.f,0.f,0.f,0.f};
    {
      bf16x8 aP0 = *(const bf16x8*)&pH[lh*40 + quad*8];
      bf16x8 aP1 = *(const bf16x8*)&pL[lh*40 + quad*8];
      const int o = quad*8;
      bf16x8 bH,bL;
      bH=*(const bf16x8*)(W0iH+(size_t)cR*32+o); bL=*(const bf16x8*)(W0iL+(size_t)cR*32+o);
      xR=MFMA(aP0,bH,xR); xR=MFMA(aP1,bH,xR); xR=MFMA(aP0,bL,xR);
      bH=*(const bf16x8*)(W0iH+(size_t)cZ*32+o); bL=*(const bf16x8*)(W0iL+(size_t)cZ*32+o);
      xZ=MFMA(aP0,bH,xZ); xZ=MFMA(aP1,bH,xZ); xZ=MFMA(aP0,bL,xZ);
      bH=*(const bf16x8*)(W0iH+(size_t)cN*32+o); bL=*(const bf16x8*)(W0iL+(size_t)cN*32+o);
      xNi=MFMA(aP0,bH,xNi); xNi=MFMA(aP1,bH,xNi); xNi=MFMA(aP0,bL,xNi);
    }
#pragma unroll
    for (int ks=0;ks<4;++ks){
      bf16x8 aH = *(const bf16x8*)&h1H[lh*136 + ks*32 + quad*8];
      bf16x8 aL = *(const bf16x8*)&h1L[lh*136 + ks*32 + quad*8];
      xR =MFMA(aH,a0RH[ks],xR);  xR =MFMA(aL,a0RH[ks],xR);  xR =MFMA(aH,a0RL[ks],xR);
      xZ =MFMA(aH,a0ZH[ks],xZ);  xZ =MFMA(aL,a0ZH[ks],xZ);  xZ =MFMA(aH,a0ZL[ks],xZ);
      xNh=MFMA(aH,a0NH[ks],xNh); xNh=MFMA(aL,a0NH[ks],xNh); xNh=MFMA(aH,a0NL[ks],xNh);
    }
    float h1n[4];
#pragma unroll
    for (int r=0;r<4;++r){
      const int m = quad*4+r;
      float rr = sigm_(xR[r] + b1R);
      float z  = sigm_(xZ[r] + b1Z);
      float nn = tanh_(xNi[r] + b1Ni + rr*(xNh[r] + b1Nh));
      float hold = (float)h1H[m*136+jc] + (float)h1L[m*136+jc];
      h1n[r] = fin_((1.f-z)*nn + z*hold);
    }
    __syncthreads();                       // B1: h1/pred reads done
#pragma unroll
    for (int r=0;r<4;++r){
      const int m = quad*4+r;
      bf16 hi=(bf16)h1n[r];
      h1H[m*136+jc]=hi; h1L[m*136+jc]=(bf16)(h1n[r]-(float)hi);
    }
    __syncthreads();                       // B2: h1(t) visible
    // ---- cell2: gi = h1(t)@W1i (streamed), gh = h2@W1h (resident) ----
    xR=(f32x4){0.f,0.f,0.f,0.f}; xZ=(f32x4){0.f,0.f,0.f,0.f};
    xNi=(f32x4){0.f,0.f,0.f,0.f}; xNh=(f32x4){0.f,0.f,0.f,0.f};
#pragma unroll
    for (int ks=0;ks<4;++ks){
      const int o = ks*32 + quad*8;
      bf16x8 aH = *(const bf16x8*)&h1H[lh*136 + o];
      bf16x8 aL = *(const bf16x8*)&h1L[lh*136 + o];
      bf16x8 bH,bL;
      bH=*(const bf16x8*)(W1iH+(size_t)cR*128+o); bL=*(const bf16x8*)(W1iL+(size_t)cR*128+o);
      xR=MFMA(aH,bH,xR); xR=MFMA(aL,bH,xR); xR=MFMA(aH,bL,xR);
      bH=*(const bf16x8*)(W1iH+(size_t)cZ*128+o); bL=*(const bf16x8*)(W1iL+(size_t)cZ*128+o);
      xZ=MFMA(aH,bH,xZ); xZ=MFMA(aL,bH,xZ); xZ=MFMA(aH,bL,xZ);
      bH=*(const bf16x8*)(W1iH+(size_t)cN*128+o); bL=*(const bf16x8*)(W1iL+(size_t)cN*128+o);
      xNi=MFMA(aH,bH,xNi); xNi=MFMA(aL,bH,xNi); xNi=MFMA(aH,bL,xNi);
    }
#pragma unroll
    for (int ks=0;ks<4;++ks){
      bf16x8 aH = *(const bf16x8*)&h2H[lh*136 + ks*32 + quad*8];
      bf16x8 aL = *(const bf16x8*)&h2L[lh*136 + ks*32 + quad*8];
      xR =MFMA(aH,a1RH[ks],xR);  xR =MFMA(aL,a1RH[ks],xR);  xR =MFMA(aH,a1RL[ks],xR);
      xZ =MFMA(aH,a1ZH[ks],xZ);  xZ =MFMA(aL,a1ZH[ks],xZ);  xZ =MFMA(aH,a1ZL[ks],xZ);
      xNh=MFMA(aH,a1NH[ks],xNh); xNh=MFMA(aL,a1NH[ks],xNh); xNh=MFMA(aH,a1NL[ks],xNh);
    }
    float h2n[4];
#pragma unroll
    for (int r=0;r<4;++r){
      const int m = quad*4+r;
      float rr = sigm_(xR[r] + b2R);
      float z  = sigm_(xZ[r] + b2Z);
      float nn = tanh_(xNi[r] + b2Ni + rr*(xNh[r] + b2Nh));
      float hold = (float)h2H[m*136+jc] + (float)h2L[m*136+jc];
      h2n[r] = fin_((1.f-z)*nn + z*hold);
    }
    __syncthreads();                       // B3: h2 reads done
#pragma unroll
    for (int r=0;r<4;++r){
      const int m = quad*4+r;
      bf16 hi=(bf16)h2n[r];
      h2H[m*136+jc]=hi; h2L[m*136+jc]=(bf16)(h2n[r]-(float)hi);
    }
    __syncthreads();                       // B4: h2(t) visible
    // ---- out: pred = h2(t)@Wo^T + bout (waves 0,1) ----
    if (wave<2){
      f32x4 po={0.f,0.f,0.f,0.f};
#pragma unroll
      for (int ks=0;ks<4;++ks){
        const int o = ks*32 + quad*8;
        bf16x8 oH = *(const bf16x8*)&h2H[lh*136 + o];
        bf16x8 oL = *(const bf16x8*)&h2L[lh*136 + o];
        bf16x8 bH = *(const bf16x8*)(WoH + (size_t)(wave*16+lh)*128 + o);
        bf16x8 bL = *(const bf16x8*)(WoL + (size_t)(wave*16+lh)*128 + o);
        po=MFMA(oH,bH,po); po=MFMA(oL,bH,po); po=MFMA(oH,bL,po);
      }
#pragma unroll
      for (int r=0;r<4;++r){
        const int m = quad*4+r;
        float pv = fin_(po[r]+bo);
        rec[((size_t)(b0+m)*512 + t)*32 + wave*16+lh] = pv;
        bf16 hi=(bf16)pv;
        pH[m*40 + wave*16+lh]=hi; pL[m*40 + wave*16+lh]=(bf16)(pv-(float)hi);
      }
    }
    __syncthreads();                       // B5: pred(t) visible
  }
}

// ---------------------------------------------------------------------------
extern "C" void kernel_launch(void* const* d_in, const int* in_sizes, int n_in,
                              void* d_out, int out_size, void* d_ws, size_t ws_size,
                              hipStream_t stream)
{
  const float* x       = (const float*)d_in[0];
  const int*   lengths = (const int*)d_in[1];
  const float* eps     = (const float*)d_in[2];
  const float* eWih0   = (const float*)d_in[3];   // [2,384,32]
  const float* eWhh0   = (const float*)d_in[4];   // [2,384,128]
  const float* ebih0   = (const float*)d_in[5];   // [2,384]
  const float* ebhh0   = (const float*)d_in[6];
  const float* eWih12  = (const float*)d_in[7];   // [2,2,384,256]
  const float* eWhh12  = (const float*)d_in[8];   // [2,2,384,128]
  const float* ebih12  = (const float*)d_in[9];   // [2,2,384]
  const float* ebhh12  = (const float*)d_in[10];
  const float* dWih0   = (const float*)d_in[11];
  const float* dWhh0   = (const float*)d_in[12];
  const float* dbih0   = (const float*)d_in[13];
  const float* dbhh0   = (const float*)d_in[14];
  const float* dWih1   = (const float*)d_in[15];
  const float* dWhh1   = (const float*)d_in[16];
  const float* dbih1   = (const float*)d_in[17];
  const float* dbhh1   = (const float*)d_in[18];
  const float* Wm      = (const float*)d_in[19];
  const float* bm      = (const float*)d_in[20];
  const float* Wl      = (const float*)d_in[21];
  const float* bl      = (const float*)d_in[22];
  const float* Wz      = (const float*)d_in[23];
  const float* bz      = (const float*)d_in[24];
  const float* Wo      = (const float*)d_in[25];
  const float* bo      = (const float*)d_in[26];

  // ws layout: [0,4M) bf16 hi/lo weight planes; [4M,68M) seqA; [68M,132M) seqB.
  // hF/hB/hInit fp32 overlay seqA (dead after enc1 reads it).
  char* ws = (char*)d_ws;
  bf16* P     = (bf16*)ws;
  bf16* seqA  = (bf16*)(ws + (size_t)(4<<20));
  bf16* seqB  = (bf16*)(ws + (size_t)(68<<20));
  float* hF    = (float*)seqA;
  float* hB    = hF + 256*128;
  float* hInit = hB + 256*128;

  const size_t O_eWih0  = 0;        // n 24576
  const size_t O_eWhh0  = 49152;    // n 98304
  const size_t O_eWih12 = 245760;   // n 393216
  const size_t O_eWhh12 = 1032192;  // n 196608
  const size_t O_dWih0  = 1425408;  // n 12288
  const size_t O_dWhh0  = 1449984;  // n 49152
  const size_t O_dWih1  = 1548288;  // n 49152
  const size_t O_dWhh1  = 1646592;  // n 49152
  const size_t O_Wout   = 1744896;  // n 4096

  float* out   = (float*)d_out;
  float* rec   = out;                      // [256,512,32]
  float* omean = out + (size_t)4194304;    // [256,32]
  float* ologv = omean + 8192;             // [256,32]

  // zero seq buffers (invalid positions are read-then-masked by consumers)
  size_t zoff = (size_t)(4<<20);
  size_t zbytes = (size_t)(128<<20);
  if (zoff + zbytes > ws_size) zbytes = (ws_size > zoff)? ws_size - zoff : 0;
  hipMemsetAsync(ws + zoff, 0, zbytes, stream);

  // weight prep
  PrepJobs J;
  const float* srcs[9] = {eWih0, eWhh0, eWih12, eWhh12, dWih0, dWhh0, dWih1, dWhh1, Wo};
  const size_t offs[9] = {O_eWih0,O_eWhh0,O_eWih12,O_eWhh12,O_dWih0,O_dWhh0,O_dWih1,O_dWhh1,O_Wout};
  const int    ns[9]   = {24576, 98304, 393216, 196608, 12288, 49152, 49152, 49152, 4096};
  for (int j=0;j<9;++j){ J.src[j]=srcs[j]; J.hi[j]=P+offs[j]; J.lo[j]=P+offs[j]+ns[j]; J.n[j]=ns[j]; }
  prep_w<<<256, 256, 0, stream>>>(J);

  dim3 blk(512);

  // encoder layer 0 (x fp32, K=32)
  enc_rec<32,true><<<32, blk, 0, stream>>>(x, seqA,
      P+O_eWih0, P+O_eWih0+24576, P+O_eWhh0, P+O_eWhh0+98304,
      ebih0, ebhh0, lengths, nullptr, nullptr);
  // encoder layer 1 (seqA bf16, K=256)
  enc_rec<256,false><<<32, blk, 0, stream>>>(seqA, seqB,
      P+O_eWih12, P+O_eWih12+393216, P+O_eWhh12, P+O_eWhh12+196608,
      ebih12, ebhh12, lengths, nullptr, nullptr);
  // encoder layer 2 (seqB, K=256; final hidden only -> hF/hB in dead seqA)
  enc_rec<256,false><<<32, blk, 0, stream>>>(seqB, nullptr,
      P+O_eWih12+196608, P+O_eWih12+393216+196608,
      P+O_eWhh12+98304,  P+O_eWhh12+196608+98304,
      ebih12+768, ebhh12+768, lengths, hF, hB);
  // latent (all fp32)
  latent_k<<<256, 64, 0, stream>>>(hF, hB, eps, Wm, bm, Wl, bl, Wz, bz,
                                   omean, ologv, hInit);
  // decoder
  dec_rec<<<16, blk, 0, stream>>>(hInit,
      P+O_dWih0, P+O_dWih0+12288, P+O_dWhh0, P+O_dWhh0+49152,
      P+O_dWih1, P+O_dWih1+49152, P+O_dWhh1, P+O_dWhh1+49152,
      P+O_Wout,  P+O_Wout+4096,
      dbih0, dbhh0, dbih1, dbhh1, bo, rec);
}

// Round 7
// 9802.747 us; speedup vs baseline: 3.2535x; 1.0458x over previous
//
#include <hip/hip_runtime.h>
#include <hip/hip_bf16.h>

// VRAE forward on gfx950. FP32 I/O; MFMA via bf16 hi/lo planes (~fp32 accuracy).
// R7: force TRUE weight residency. R6's VGPR_Count=128 proved the compiler
// rematerialized the "resident" weight loads every step (590 KB/step L2 re-stream).
// Fix: asm-pin resident frags (dec: W0h+W1h hi/lo = 192 VGPR; enc: Whh = 96 VGPR),
// W1i-hi in LDS (loaded once, stride-136 padded), dec restructured to 3 barriers/step
// with gh1/gh2 precomputed in the out-proj phase (pipelined across steps).

typedef __bf16 bf16;
typedef __bf16 bf16x8 __attribute__((ext_vector_type(8)));
typedef float f32x4 __attribute__((ext_vector_type(4)));

#define MFMA(a,b,c) __builtin_amdgcn_mfma_f32_16x16x32_bf16((a),(b),(c),0,0,0)
#define Z4 (f32x4){0.f,0.f,0.f,0.f}

__device__ __forceinline__ float sigm_(float x){ return 1.f/(1.f+__expf(-x)); }
__device__ __forceinline__ float tanh_(float x){
  x = fminf(15.f, fmaxf(-15.f, x));
  float e = __expf(2.f*x);
  return (e-1.f)/(e+1.f);
}
__device__ __forceinline__ float fin_(float v){ return (v - v == 0.0f) ? v : 0.0f; }
// anti-rematerialization pin: makes the loaded value opaque so the register
// allocator must keep it live instead of re-loading from memory each iteration.
__device__ __forceinline__ void pin_(bf16x8 &v){ asm volatile("" : "+v"(v)); }

// ---------------------------------------------------------------------------
// Weight prep: fp32 -> bf16 hi/lo planes in ws.
// ---------------------------------------------------------------------------
struct PrepJobs {
  const float* src[9];
  bf16* hi[9];
  bf16* lo[9];
  int n[9];
};

__global__ void prep_w(PrepJobs J){
  const int stride = gridDim.x*blockDim.x;
  const int t0 = blockIdx.x*blockDim.x + threadIdx.x;
  for (int j=0;j<9;++j){
    const float* __restrict__ s = J.src[j];
    bf16* __restrict__ h = J.hi[j];
    bf16* __restrict__ l = J.lo[j];
    const int n = J.n[j];
    for (int i=t0;i<n;i+=stride){
      float v = fin_(s[i]);
      bf16 hh = (bf16)v;
      h[i] = hh;
      l[i] = (bf16)(v - (float)hh);
    }
  }
}

// ---------------------------------------------------------------------------
// Encoder recurrent kernel. grid=32: blockIdx>>4 = dir, blockIdx&15 = batch
// slice of 16. block=512 (8 waves). Wave w owns gate triplet {w,8+w,16+w}.
// Whh hi/lo register-resident (PINNED); Wih swept once per 4 steps (gi burst).
// ---------------------------------------------------------------------------
template<int KIN, bool F32IN>
__global__ __launch_bounds__(512,2)
void enc_rec(const void* __restrict__ seqIn_,  // [256,512,KIN] fp32|bf16
             bf16* __restrict__ seqOut,        // [256,512,256] or null
             const bf16* __restrict__ WihHi_, const bf16* __restrict__ WihLo_, // [2,384,KIN]
             const bf16* __restrict__ WhhHi_, const bf16* __restrict__ WhhLo_, // [2,384,128]
             const float* __restrict__ bih_, const float* __restrict__ bhh_,   // [2,384]
             const int* __restrict__ lengths,
             float* __restrict__ hFo, float* __restrict__ hBo)                 // [256,128] or null
{
  constexpr int NKS  = KIN/32;
  constexpr int XSTR = F32IN ? 40 : 264;
  constexpr int XPL  = 16*XSTR;
  constexpr int XSLOT= (F32IN?2:1)*XPL;
  const int tid = threadIdx.x;
  const int wave = tid>>6;
  const int lh   = tid&15;
  const int quad = (tid>>4)&3;
  const int dir  = blockIdx.x>>4;
  const int b0   = (blockIdx.x&15)*16;

  const bf16* __restrict__ WihHi = WihHi_ + (size_t)dir*384*KIN;
  const bf16* __restrict__ WihLo = WihLo_ + (size_t)dir*384*KIN;
  const bf16* __restrict__ WhhHi = WhhHi_ + (size_t)dir*384*128;
  const bf16* __restrict__ WhhLo = WhhLo_ + (size_t)dir*384*128;
  const float* __restrict__ bih = bih_ + dir*384;
  const float* __restrict__ bhh = bhh_ + dir*384;

  __shared__ bf16 hHi[16*136], hLo[16*136];
  __shared__ bf16 xb[4*XSLOT];

  const int jc = wave*16 + lh;
  const int cR = jc, cZ = 128+jc, cN = 256+jc;

  // resident Whh hi/lo frags (24 frags = 96 VGPR) — PINNED
  bf16x8 wRH[4],wRL[4],wZH[4],wZL[4],wNH[4],wNL[4];
#pragma unroll
  for (int ks=0;ks<4;++ks){
    const int o = ks*32 + quad*8;
    wRH[ks]=*(const bf16x8*)(WhhHi+(size_t)cR*128+o); wRL[ks]=*(const bf16x8*)(WhhLo+(size_t)cR*128+o);
    wZH[ks]=*(const bf16x8*)(WhhHi+(size_t)cZ*128+o); wZL[ks]=*(const bf16x8*)(WhhLo+(size_t)cZ*128+o);
    wNH[ks]=*(const bf16x8*)(WhhHi+(size_t)cN*128+o); wNL[ks]=*(const bf16x8*)(WhhLo+(size_t)cN*128+o);
    pin_(wRH[ks]); pin_(wRL[ks]); pin_(wZH[ks]); pin_(wZL[ks]); pin_(wNH[ks]); pin_(wNL[ks]);
  }
  const float bR  = bih[cR]+bhh[cR];
  const float bZc = bih[cZ]+bhh[cZ];
  const float bNi = bih[cN];
  const float bNh = bhh[cN];

  int lenRow[4];
#pragma unroll
  for (int r=0;r<4;++r) lenRow[r] = lengths[b0 + quad*4 + r];
  const int lenA = lengths[b0+lh];
  const int Tmax = lengths[b0];
  const int TT   = (Tmax+3)&~3;

  const int wrow = (tid>>4)&15;
  const int wcol = (tid&15)*8;
  const int lenW = lengths[b0 + wrow];
  const int srow = tid>>5;
  const int scol = tid&31;
  const int lenS = lengths[b0 + srow];

  for (int i=tid;i<16*136;i+=512){ hHi[i]=(bf16)0.f; hLo[i]=(bf16)0.f; }

  auto stage = [&](int slot, int sabs){
    int tb = dir ? (lenS-1-sabs) : sabs;
    tb = tb<0 ? 0 : (tb>511 ? 511 : tb);
    if constexpr (F32IN){
      float v = ((const float*)seqIn_)[((size_t)(b0+srow)*512+tb)*32 + scol];
      bf16 hh=(bf16)v;
      xb[slot*XSLOT + srow*XSTR + scol] = hh;
      xb[slot*XSLOT + XPL + srow*XSTR + scol] = (bf16)(v-(float)hh);
    } else {
      bf16x8 v = *(const bf16x8*)((const bf16*)seqIn_ + ((size_t)(b0+srow)*512+tb)*256 + scol*8);
      *(bf16x8*)&xb[slot*XSLOT + srow*XSTR + scol*8] = v;
    }
  };
#pragma unroll
  for (int s=0;s<4;++s) stage(s, 1+s);

  f32x4 accR[4], accZ[4], giN[4];
#pragma unroll
  for (int s=0;s<4;++s){ accR[s]=Z4; accZ[s]=Z4; giN[s]=Z4; }

  // prologue: gi(0) -> slot 3
  {
    int tb0 = dir ? (lenA-1) : 0; tb0 = tb0<0?0:tb0;
#pragma unroll
    for (int ks=0;ks<NKS;++ks){
      const int o = ks*32 + quad*8;
      bf16x8 axH, axL;
      if constexpr (F32IN){
        const float* ap = (const float*)seqIn_ + ((size_t)(b0+lh)*512+tb0)*KIN + o;
#pragma unroll
        for (int e=0;e<8;++e){ float v=ap[e]; bf16 hh=(bf16)v; axH[e]=hh; axL[e]=(bf16)(v-(float)hh); }
      } else {
        axH = *(const bf16x8*)((const bf16*)seqIn_ + ((size_t)(b0+lh)*512+tb0)*KIN + o);
      }
      bf16x8 bH, bL;
      bH=*(const bf16x8*)(WihHi+(size_t)cR*KIN+o); bL=*(const bf16x8*)(WihLo+(size_t)cR*KIN+o);
      accR[3]=MFMA(axH,bH,accR[3]); if constexpr(F32IN) accR[3]=MFMA(axL,bH,accR[3]); accR[3]=MFMA(axH,bL,accR[3]);
      bH=*(const bf16x8*)(WihHi+(size_t)cZ*KIN+o); bL=*(const bf16x8*)(WihLo+(size_t)cZ*KIN+o);
      accZ[3]=MFMA(axH,bH,accZ[3]); if constexpr(F32IN) accZ[3]=MFMA(axL,bH,accZ[3]); accZ[3]=MFMA(axH,bL,accZ[3]);
      bH=*(const bf16x8*)(WihHi+(size_t)cN*KIN+o); bL=*(const bf16x8*)(WihLo+(size_t)cN*KIN+o);
      giN[3]=MFMA(axH,bH,giN[3]);  if constexpr(F32IN) giN[3]=MFMA(axL,bH,giN[3]);  giN[3]=MFMA(axH,bL,giN[3]);
    }
  }
  __syncthreads();

  for (int t4=0; t4<TT; t4+=4){
#pragma unroll
    for (int p=0;p<4;++p){
      const int t = t4 + p;
      const int s = (p+3)&3;
      if (seqOut && tid<256 && t>0 && (t-1)<lenW){
        const int tp = t-1;
        const int tb = dir ? (lenW-1-tp) : tp;
        bf16x8 v = *(const bf16x8*)&hHi[wrow*136 + wcol];
        *(bf16x8*)(seqOut + ((size_t)(b0+wrow)*512 + tb)*256 + dir*128 + wcol) = v;
      }
      f32x4 gN = Z4;
#pragma unroll
      for (int ks=0;ks<4;++ks){
        bf16x8 aH = *(const bf16x8*)&hHi[lh*136 + ks*32 + quad*8];
        bf16x8 aL = *(const bf16x8*)&hLo[lh*136 + ks*32 + quad*8];
        accR[s]=MFMA(aH,wRH[ks],accR[s]); accR[s]=MFMA(aL,wRH[ks],accR[s]); accR[s]=MFMA(aH,wRL[ks],accR[s]);
        accZ[s]=MFMA(aH,wZH[ks],accZ[s]); accZ[s]=MFMA(aL,wZH[ks],accZ[s]); accZ[s]=MFMA(aH,wZL[ks],accZ[s]);
        gN     =MFMA(aH,wNH[ks],gN);      gN     =MFMA(aL,wNH[ks],gN);      gN     =MFMA(aH,wNL[ks],gN);
      }
      float hsel[4];
#pragma unroll
      for (int r=0;r<4;++r){
        const int m = quad*4 + r;
        float rr = sigm_(accR[s][r] + bR);
        float zz = sigm_(accZ[s][r] + bZc);
        float nn = tanh_(giN[s][r] + bNi + rr*(gN[r] + bNh));
        float hold = (float)hHi[m*136+jc] + (float)hLo[m*136+jc];
        float hnew = fin_((1.f-zz)*nn + zz*hold);
        hsel[r] = (t < lenRow[r]) ? hnew : hold;
      }
      if (p==0){
#pragma unroll
        for (int s2=0;s2<4;++s2){ accR[s2]=Z4; accZ[s2]=Z4; giN[s2]=Z4; }
#pragma unroll
        for (int ks=0;ks<NKS;++ks){
          const int o = ks*32 + quad*8;
          bf16x8 axH[4], axL[F32IN?4:1];
#pragma unroll
          for (int s2=0;s2<4;++s2){
            axH[s2] = *(const bf16x8*)&xb[s2*XSLOT + lh*XSTR + o];
            if constexpr (F32IN) axL[s2] = *(const bf16x8*)&xb[s2*XSLOT + XPL + lh*XSTR + o];
          }
          bf16x8 bH, bL;
          bH=*(const bf16x8*)(WihHi+(size_t)cR*KIN+o); bL=*(const bf16x8*)(WihLo+(size_t)cR*KIN+o);
#pragma unroll
          for (int s2=0;s2<4;++s2){
            accR[s2]=MFMA(axH[s2],bH,accR[s2]);
            if constexpr(F32IN) accR[s2]=MFMA(axL[s2],bH,accR[s2]);
            accR[s2]=MFMA(axH[s2],bL,accR[s2]);
          }
          bH=*(const bf16x8*)(WihHi+(size_t)cZ*KIN+o); bL=*(const bf16x8*)(WihLo+(size_t)cZ*KIN+o);
#pragma unroll
          for (int s2=0;s2<4;++s2){
            accZ[s2]=MFMA(axH[s2],bH,accZ[s2]);
            if constexpr(F32IN) accZ[s2]=MFMA(axL[s2],bH,accZ[s2]);
            accZ[s2]=MFMA(axH[s2],bL,accZ[s2]);
          }
          bH=*(const bf16x8*)(WihHi+(size_t)cN*KIN+o); bL=*(const bf16x8*)(WihLo+(size_t)cN*KIN+o);
#pragma unroll
          for (int s2=0;s2<4;++s2){
            giN[s2]=MFMA(axH[s2],bH,giN[s2]);
            if constexpr(F32IN) giN[s2]=MFMA(axL[s2],bH,giN[s2]);
            giN[s2]=MFMA(axH[s2],bL,giN[s2]);
          }
        }
      }
      __syncthreads();     // B1: all reads of h(t-1) done
#pragma unroll
      for (int r=0;r<4;++r){
        const int m = quad*4 + r;
        bf16 hi = (bf16)hsel[r];
        hHi[m*136+jc] = hi;
        hLo[m*136+jc] = (bf16)(hsel[r]-(float)hi);
      }
      if      (p==1){ stage(0, t4+5); stage(1, t4+6); }
      else if (p==2){ stage(2, t4+7); }
      else if (p==3){ stage(3, t4+8); }
      __syncthreads();     // B2: h(t) + staged x visible
    }
  }
  if (seqOut && tid<256 && (TT-1)<lenW){
    const int tb = dir ? (lenW-1-(TT-1)) : (TT-1);
    bf16x8 v = *(const bf16x8*)&hHi[wrow*136 + wcol];
    *(bf16x8*)(seqOut + ((size_t)(b0+wrow)*512 + tb)*256 + dir*128 + wcol) = v;
  }
  float* hout = dir ? hBo : hFo;
  if (hout && tid<256){
#pragma unroll
    for (int e=0;e<8;++e){
      const int j = wcol+e;
      hout[(size_t)(b0+wrow)*128 + j] = fin_((float)hHi[wrow*136+j] + (float)hLo[wrow*136+j]);
    }
  }
}

// ---------------------------------------------------------------------------
// Latent: mean/logvar/z/h_init. grid=256, block=64. fp32.
// ---------------------------------------------------------------------------
__global__ void latent_k(const float* __restrict__ hF, const float* __restrict__ hB,
                         const float* __restrict__ eps,
                         const float* __restrict__ Wm, const float* __restrict__ bm,
                         const float* __restrict__ Wl, const float* __restrict__ bl,
                         const float* __restrict__ Wz, const float* __restrict__ bz,
                         float* __restrict__ out_mean, float* __restrict__ out_logvar,
                         float* __restrict__ hInit)
{
  const int b = blockIdx.x, tid = threadIdx.x;
  __shared__ float hc[256];
  __shared__ float mv[64];
  __shared__ float zz[32];
  for (int k=tid;k<256;k+=64) hc[k] = fin_((k<128)? hF[(size_t)b*128+k] : hB[(size_t)b*128+k-128]);
  __syncthreads();
  {
    const int i = tid & 31;
    const float* W = (tid<32)? Wm : Wl;
    float acc = (tid<32)? bm[i] : bl[i];
    for (int k=0;k<256;++k) acc += hc[k]*W[i*256+k];
    acc = fin_(acc);
    mv[tid] = acc;
    if (tid<32) out_mean[b*32+i] = acc;
    else        out_logvar[b*32+(tid-32)] = acc;
  }
  __syncthreads();
  if (tid<32) zz[tid] = fin_(mv[tid] + __expf(0.5f*mv[32+tid]) * eps[b*32+tid]);
  __syncthreads();
  for (int j=tid;j<128;j+=64){
    float a = bz[j];
    for (int k=0;k<32;++k) a += zz[k]*Wz[j*32+k];
    hInit[(size_t)b*128 + j] = tanh_(fin_(a));
  }
}

// ---------------------------------------------------------------------------
// Decoder: 2-layer GRU + out-proj, T=512. grid=16, block=512 (8 waves).
// Wave w owns triplet {w,8+w,16+w}. W0h+W1h PINNED resident; W1i-hi in LDS;
// 3 barriers/step; gh1/gh2 for step t+1 precomputed during out-proj phase.
// ---------------------------------------------------------------------------
__global__ __launch_bounds__(512,2)
void dec_rec(const float* __restrict__ hInit,
             const bf16* __restrict__ W0iH, const bf16* __restrict__ W0iL,  // [384,32]
             const bf16* __restrict__ W0hH, const bf16* __restrict__ W0hL,  // [384,128]
             const bf16* __restrict__ W1iH, const bf16* __restrict__ W1iL,  // [384,128]
             const bf16* __restrict__ W1hH, const bf16* __restrict__ W1hL,  // [384,128]
             const bf16* __restrict__ WoH,  const bf16* __restrict__ WoL,   // [32,128]
             const float* __restrict__ bih0, const float* __restrict__ bhh0,
             const float* __restrict__ bih1, const float* __restrict__ bhh1,
             const float* __restrict__ bout,
             float* __restrict__ rec)        // [256,512,32]
{
  const int tid = threadIdx.x;
  const int wave = tid>>6;
  const int lh   = tid&15;
  const int quad = (tid>>4)&3;
  const int b0 = blockIdx.x*16;
  const int jc = wave*16 + lh;
  const int cR = jc, cZ = 128+jc, cN = 256+jc;

  __shared__ bf16 h1H[16*136], h1L[16*136], h2H[16*136], h2L[16*136];
  __shared__ bf16 pH[16*40], pL[16*40];
  __shared__ bf16 w1iLds[384*136];   // W1i-hi plane, stride-136 padded (~104 KB)

  // resident W0h, W1h hi/lo (48 frags = 192 VGPR) — PINNED
  bf16x8 a0RH[4],a0RL[4],a0ZH[4],a0ZL[4],a0NH[4],a0NL[4];
  bf16x8 a1RH[4],a1RL[4],a1ZH[4],a1ZL[4],a1NH[4],a1NL[4];
#pragma unroll
  for (int ks=0;ks<4;++ks){
    const int o = ks*32 + quad*8;
    a0RH[ks]=*(const bf16x8*)(W0hH+(size_t)cR*128+o); a0RL[ks]=*(const bf16x8*)(W0hL+(size_t)cR*128+o);
    a0ZH[ks]=*(const bf16x8*)(W0hH+(size_t)cZ*128+o); a0ZL[ks]=*(const bf16x8*)(W0hL+(size_t)cZ*128+o);
    a0NH[ks]=*(const bf16x8*)(W0hH+(size_t)cN*128+o); a0NL[ks]=*(const bf16x8*)(W0hL+(size_t)cN*128+o);
    a1RH[ks]=*(const bf16x8*)(W1hH+(size_t)cR*128+o); a1RL[ks]=*(const bf16x8*)(W1hL+(size_t)cR*128+o);
    a1ZH[ks]=*(const bf16x8*)(W1hH+(size_t)cZ*128+o); a1ZL[ks]=*(const bf16x8*)(W1hL+(size_t)cZ*128+o);
    a1NH[ks]=*(const bf16x8*)(W1hH+(size_t)cN*128+o); a1NL[ks]=*(const bf16x8*)(W1hL+(size_t)cN*128+o);
    pin_(a0RH[ks]); pin_(a0RL[ks]); pin_(a0ZH[ks]); pin_(a0ZL[ks]); pin_(a0NH[ks]); pin_(a0NL[ks]);
    pin_(a1RH[ks]); pin_(a1RL[ks]); pin_(a1ZH[ks]); pin_(a1ZL[ks]); pin_(a1NH[ks]); pin_(a1NL[ks]);
  }
  const float b1R = bih0[cR]+bhh0[cR], b1Z = bih0[cZ]+bhh0[cZ], b1Ni = bih0[cN], b1Nh = bhh0[cN];
  const float b2R = bih1[cR]+bhh1[cR], b2Z = bih1[cZ]+bhh1[cZ], b2Ni = bih1[cN], b2Nh = bhh1[cN];
  const float bo = (wave<2) ? bout[wave*16+lh] : 0.f;

  // stage W1i-hi into LDS (once)
  for (int i=tid; i<384*16; i+=512){
    const int rr = i>>4, k8 = (i&15)*8;
    *(bf16x8*)&w1iLds[rr*136 + k8] = *(const bf16x8*)(W1iH + (size_t)rr*128 + k8);
  }
  // init h1,h2 from hInit; pred = 0
  if (tid < 256){
    const int row = (tid>>4)&15;
    const int c0  = (tid&15)*8;
#pragma unroll
    for (int e=0;e<8;++e){
      const int j = c0+e;
      float v = fin_(hInit[(size_t)(b0+row)*128 + j]);
      bf16 hi=(bf16)v, lo=(bf16)(v-(float)hi);
      h1H[row*136+j]=hi; h1L[row*136+j]=lo;
      h2H[row*136+j]=hi; h2L[row*136+j]=lo;
    }
  }
  for (int i=tid;i<16*40;i+=512){ pH[i]=(bf16)0.f; pL[i]=(bf16)0.f; }
  __syncthreads();

  // persistent gate accumulators (gh precomputed, gi appended)
  f32x4 c1R, c1Z, c1Nh, c2R, c2Z, c2Nh;

  auto ghpre = [&](){
    c1R=Z4; c1Z=Z4; c1Nh=Z4; c2R=Z4; c2Z=Z4; c2Nh=Z4;
#pragma unroll
    for (int ks=0;ks<4;++ks){
      const int o = ks*32 + quad*8;
      bf16x8 aH = *(const bf16x8*)&h1H[lh*136 + o];
      bf16x8 aL = *(const bf16x8*)&h1L[lh*136 + o];
      c1R =MFMA(aH,a0RH[ks],c1R);  c1R =MFMA(aL,a0RH[ks],c1R);  c1R =MFMA(aH,a0RL[ks],c1R);
      c1Z =MFMA(aH,a0ZH[ks],c1Z);  c1Z =MFMA(aL,a0ZH[ks],c1Z);  c1Z =MFMA(aH,a0ZL[ks],c1Z);
      c1Nh=MFMA(aH,a0NH[ks],c1Nh); c1Nh=MFMA(aL,a0NH[ks],c1Nh); c1Nh=MFMA(aH,a0NL[ks],c1Nh);
    }
#pragma unroll
    for (int ks=0;ks<4;++ks){
      const int o = ks*32 + quad*8;
      bf16x8 aH = *(const bf16x8*)&h2H[lh*136 + o];
      bf16x8 aL = *(const bf16x8*)&h2L[lh*136 + o];
      c2R =MFMA(aH,a1RH[ks],c2R);  c2R =MFMA(aL,a1RH[ks],c2R);  c2R =MFMA(aH,a1RL[ks],c2R);
      c2Z =MFMA(aH,a1ZH[ks],c2Z);  c2Z =MFMA(aL,a1ZH[ks],c2Z);  c2Z =MFMA(aH,a1ZL[ks],c2Z);
      c2Nh=MFMA(aH,a1NH[ks],c2Nh); c2Nh=MFMA(aL,a1NH[ks],c2Nh); c2Nh=MFMA(aH,a1NL[ks],c2Nh);
    }
  };
  ghpre();   // gh for t=0 (reads initial h1,h2; post-barrier)

  for (int t=0;t<512;++t){
    // ---- P1: gi1 (pred, K=32) + gates1 + write h1(t). hold = own-lane read. ----
    {
      f32x4 c1Ni = Z4;
      bf16x8 aP0 = *(const bf16x8*)&pH[lh*40 + quad*8];
      bf16x8 aP1 = *(const bf16x8*)&pL[lh*40 + quad*8];
      const int o = quad*8;
      bf16x8 bH,bL;
      bH=*(const bf16x8*)(W0iH+(size_t)cR*32+o); bL=*(const bf16x8*)(W0iL+(size_t)cR*32+o);
      c1R=MFMA(aP0,bH,c1R); c1R=MFMA(aP1,bH,c1R); c1R=MFMA(aP0,bL,c1R);
      bH=*(const bf16x8*)(W0iH+(size_t)cZ*32+o); bL=*(const bf16x8*)(W0iL+(size_t)cZ*32+o);
      c1Z=MFMA(aP0,bH,c1Z); c1Z=MFMA(aP1,bH,c1Z); c1Z=MFMA(aP0,bL,c1Z);
      bH=*(const bf16x8*)(W0iH+(size_t)cN*32+o); bL=*(const bf16x8*)(W0iL+(size_t)cN*32+o);
      c1Ni=MFMA(aP0,bH,c1Ni); c1Ni=MFMA(aP1,bH,c1Ni); c1Ni=MFMA(aP0,bL,c1Ni);
#pragma unroll
      for (int r=0;r<4;++r){
        const int m = quad*4+r;
        float rr = sigm_(c1R[r] + b1R);
        float z  = sigm_(c1Z[r] + b1Z);
        float nn = tanh_(c1Ni[r] + b1Ni + rr*(c1Nh[r] + b1Nh));
        float hold = (float)h1H[m*136+jc] + (float)h1L[m*136+jc];
        float hnew = fin_((1.f-z)*nn + z*hold);
        bf16 hi=(bf16)hnew;
        h1H[m*136+jc]=hi; h1L[m*136+jc]=(bf16)(hnew-(float)hi);
      }
    }
    __syncthreads();                       // B1: h1(t) visible
    // ---- P2: gi2 (h1(t), K=128; W1i-hi from LDS, lo from L2) + gates2 + write h2(t) ----
    {
      f32x4 c2Ni = Z4;
#pragma unroll
      for (int ks=0;ks<4;++ks){
        const int o = ks*32 + quad*8;
        bf16x8 aH = *(const bf16x8*)&h1H[lh*136 + o];
        bf16x8 aL = *(const bf16x8*)&h1L[lh*136 + o];
        bf16x8 bH,bL;
        bH=*(const bf16x8*)&w1iLds[cR*136+o]; bL=*(const bf16x8*)(W1iL+(size_t)cR*128+o);
        c2R=MFMA(aH,bH,c2R); c2R=MFMA(aL,bH,c2R); c2R=MFMA(aH,bL,c2R);
        bH=*(const bf16x8*)&w1iLds[cZ*136+o]; bL=*(const bf16x8*)(W1iL+(size_t)cZ*128+o);
        c2Z=MFMA(aH,bH,c2Z); c2Z=MFMA(aL,bH,c2Z); c2Z=MFMA(aH,bL,c2Z);
        bH=*(const bf16x8*)&w1iLds[cN*136+o]; bL=*(const bf16x8*)(W1iL+(size_t)cN*128+o);
        c2Ni=MFMA(aH,bH,c2Ni); c2Ni=MFMA(aL,bH,c2Ni); c2Ni=MFMA(aH,bL,c2Ni);
      }
#pragma unroll
      for (int r=0;r<4;++r){
        const int m = quad*4+r;
        float rr = sigm_(c2R[r] + b2R);
        float z  = sigm_(c2Z[r] + b2Z);
        float nn = tanh_(c2Ni[r] + b2Ni + rr*(c2Nh[r] + b2Nh));
        float hold = (float)h2H[m*136+jc] + (float)h2L[m*136+jc];
        float hnew = fin_((1.f-z)*nn + z*hold);
        bf16 hi=(bf16)hnew;
        h2H[m*136+jc]=hi; h2L[m*136+jc]=(bf16)(hnew-(float)hi);
      }
    }
    __syncthreads();                       // B2: h2(t) visible
    // ---- P3: out-proj (waves 0,1) + gh precompute for t+1 (all waves) ----
    if (wave<2){
      f32x4 po=Z4;
#pragma unroll
      for (int ks=0;ks<4;++ks){
        const int o = ks*32 + quad*8;
        bf16x8 oH = *(const bf16x8*)&h2H[lh*136 + o];
        bf16x8 oL = *(const bf16x8*)&h2L[lh*136 + o];
        bf16x8 bH = *(const bf16x8*)(WoH + (size_t)(wave*16+lh)*128 + o);
        bf16x8 bL = *(const bf16x8*)(WoL + (size_t)(wave*16+lh)*128 + o);
        po=MFMA(oH,bH,po); po=MFMA(oL,bH,po); po=MFMA(oH,bL,po);
      }
#pragma unroll
      for (int r=0;r<4;++r){
        const int m = quad*4+r;
        float pv = fin_(po[r]+bo);
        rec[((size_t)(b0+m)*512 + t)*32 + wave*16+lh] = pv;
        bf16 hi=(bf16)pv;
        pH[m*40 + wave*16+lh]=hi; pL[m*40 + wave*16+lh]=(bf16)(pv-(float)hi);
      }
    }
    if (t+1 < 512) ghpre();                // reads h1(t),h2(t) — post-B2
    __syncthreads();                       // B3: pred(t) visible; h reads done
  }
}

// ---------------------------------------------------------------------------
extern "C" void kernel_launch(void* const* d_in, const int* in_sizes, int n_in,
                              void* d_out, int out_size, void* d_ws, size_t ws_size,
                              hipStream_t stream)
{
  const float* x       = (const float*)d_in[0];
  const int*   lengths = (const int*)d_in[1];
  const float* eps     = (const float*)d_in[2];
  const float* eWih0   = (const float*)d_in[3];
  const float* eWhh0   = (const float*)d_in[4];
  const float* ebih0   = (const float*)d_in[5];
  const float* ebhh0   = (const float*)d_in[6];
  const float* eWih12  = (const float*)d_in[7];
  const float* eWhh12  = (const float*)d_in[8];
  const float* ebih12  = (const float*)d_in[9];
  const float* ebhh12  = (const float*)d_in[10];
  const float* dWih0   = (const float*)d_in[11];
  const float* dWhh0   = (const float*)d_in[12];
  const float* dbih0   = (const float*)d_in[13];
  const float* dbhh0   = (const float*)d_in[14];
  const float* dWih1   = (const float*)d_in[15];
  const float* dWhh1   = (const float*)d_in[16];
  const float* dbih1   = (const float*)d_in[17];
  const float* dbhh1   = (const float*)d_in[18];
  const float* Wm      = (const float*)d_in[19];
  const float* bm      = (const float*)d_in[20];
  const float* Wl      = (const float*)d_in[21];
  const float* bl      = (const float*)d_in[22];
  const float* Wz      = (const float*)d_in[23];
  const float* bz      = (const float*)d_in[24];
  const float* Wo      = (const float*)d_in[25];
  const float* bo      = (const float*)d_in[26];

  char* ws = (char*)d_ws;
  bf16* P     = (bf16*)ws;
  bf16* seqA  = (bf16*)(ws + (size_t)(4<<20));
  bf16* seqB  = (bf16*)(ws + (size_t)(68<<20));
  float* hF    = (float*)seqA;
  float* hB    = hF + 256*128;
  float* hInit = hB + 256*128;

  const size_t O_eWih0  = 0;
  const size_t O_eWhh0  = 49152;
  const size_t O_eWih12 = 245760;
  const size_t O_eWhh12 = 1032192;
  const size_t O_dWih0  = 1425408;
  const size_t O_dWhh0  = 1449984;
  const size_t O_dWih1  = 1548288;
  const size_t O_dWhh1  = 1646592;
  const size_t O_Wout   = 1744896;

  float* out   = (float*)d_out;
  float* rec   = out;
  float* omean = out + (size_t)4194304;
  float* ologv = omean + 8192;

  size_t zoff = (size_t)(4<<20);
  size_t zbytes = (size_t)(128<<20);
  if (zoff + zbytes > ws_size) zbytes = (ws_size > zoff)? ws_size - zoff : 0;
  hipMemsetAsync(ws + zoff, 0, zbytes, stream);

  PrepJobs J;
  const float* srcs[9] = {eWih0, eWhh0, eWih12, eWhh12, dWih0, dWhh0, dWih1, dWhh1, Wo};
  const size_t offs[9] = {O_eWih0,O_eWhh0,O_eWih12,O_eWhh12,O_dWih0,O_dWhh0,O_dWih1,O_dWhh1,O_Wout};
  const int    ns[9]   = {24576, 98304, 393216, 196608, 12288, 49152, 49152, 49152, 4096};
  for (int j=0;j<9;++j){ J.src[j]=srcs[j]; J.hi[j]=P+offs[j]; J.lo[j]=P+offs[j]+ns[j]; J.n[j]=ns[j]; }
  prep_w<<<256, 256, 0, stream>>>(J);

  dim3 blk(512);

  enc_rec<32,true><<<32, blk, 0, stream>>>(x, seqA,
      P+O_eWih0, P+O_eWih0+24576, P+O_eWhh0, P+O_eWhh0+98304,
      ebih0, ebhh0, lengths, nullptr, nullptr);
  enc_rec<256,false><<<32, blk, 0, stream>>>(seqA, seqB,
      P+O_eWih12, P+O_eWih12+393216, P+O_eWhh12, P+O_eWhh12+196608,
      ebih12, ebhh12, lengths, nullptr, nullptr);
  enc_rec<256,false><<<32, blk, 0, stream>>>(seqB, nullptr,
      P+O_eWih12+196608, P+O_eWih12+393216+196608,
      P+O_eWhh12+98304,  P+O_eWhh12+196608+98304,
      ebih12+768, ebhh12+768, lengths, hF, hB);
  latent_k<<<256, 64, 0, stream>>>(hF, hB, eps, Wm, bm, Wl, bl, Wz, bz,
                                   omean, ologv, hInit);
  dec_rec<<<16, blk, 0, stream>>>(hInit,
      P+O_dWih0, P+O_dWih0+12288, P+O_dWhh0, P+O_dWhh0+49152,
      P+O_dWih1, P+O_dWih1+49152, P+O_dWhh1, P+O_dWhh1+49152,
      P+O_Wout,  P+O_Wout+4096,
      dbih0, dbhh0, dbih1, dbhh1, bo, rec);
}